// Round 1
// baseline (1039.771 us; speedup 1.0000x reference)
//
#include <hip/hip_runtime.h>
#include <math.h>

// ---------------------------------------------------------------------------
// AttentionBlock: GroupNorm(32) -> QKV proj -> MHA(8 heads) -> out proj
// B=16, C=512, L=1024, group=16ch, head ch=64.
// Round 1: pure fp32 correctness baseline (no MFMA yet).
// ---------------------------------------------------------------------------

#define TP 68  // LDS tile stride (64 + 4 pad, keeps 16B alignment)

// ------------------------- GroupNorm ---------------------------------------
// One block per (batch, group). A group = 16 contiguous channels x 1024 = one
// contiguous 64KB chunk. Two-pass over registers (values kept in VGPRs).
__global__ __launch_bounds__(256) void gn_kernel(
    const float* __restrict__ x, const float* __restrict__ gw,
    const float* __restrict__ gb, float* __restrict__ h) {
  const int b = blockIdx.x >> 5;
  const int g = blockIdx.x & 31;
  const size_t base = ((size_t)(b * 512 + g * 16)) * 1024;
  const float4* xp = (const float4*)(x + base);
  float4* hp = (float4*)(h + base);
  const int tid = threadIdx.x;

  float4 vals[16];
  float s = 0.f, sq = 0.f;
#pragma unroll
  for (int r = 0; r < 16; ++r) {
    float4 v = xp[tid + 256 * r];
    vals[r] = v;
    s += v.x + v.y + v.z + v.w;
    sq += v.x * v.x + v.y * v.y + v.z * v.z + v.w * v.w;
  }
  __shared__ float rs[256];
  __shared__ float rq[256];
  rs[tid] = s;
  rq[tid] = sq;
  __syncthreads();
  for (int off = 128; off > 0; off >>= 1) {
    if (tid < off) {
      rs[tid] += rs[tid + off];
      rq[tid] += rq[tid + off];
    }
    __syncthreads();
  }
  const float mean = rs[0] * (1.f / 16384.f);
  const float var = rq[0] * (1.f / 16384.f) - mean * mean;
  const float rinv = rsqrtf(var + 1e-5f);
#pragma unroll
  for (int r = 0; r < 16; ++r) {
    // iteration r covers exactly channel g*16 + r (256 thr * 4 = 1024 = L)
    const int c = g * 16 + r;
    const float wc = gw[c] * rinv;
    const float bc = gb[c] - mean * wc;
    float4 v = vals[r];
    v.x = v.x * wc + bc;
    v.y = v.y * wc + bc;
    v.z = v.z * wc + bc;
    v.w = v.w * wc + bc;
    hp[tid + 256 * r] = v;
  }
}

// ------------------------- SGEMM + bias ------------------------------------
// Out[batch][m][n] = sum_k W[m][k] * X[batch][k][n] + bias[m]
// 128x128 tile, BK=16, 256 threads, 8x8 microtile per thread.
__global__ __launch_bounds__(256) void sgemm_bias(
    const float* __restrict__ W, const float* __restrict__ X,
    const float* __restrict__ bias, float* __restrict__ Out,
    int M, int K, int N) {
  __shared__ __align__(16) float As[16][132];  // [k][m], transposed store
  __shared__ __align__(16) float Bs[16][132];  // [k][n]
  const int tid = threadIdx.x;
  const int bn = blockIdx.x * 128;
  const int bm = blockIdx.y * 128;
  const int batch = blockIdx.z;
  const float* Xb = X + (size_t)batch * K * N;
  float* Ob = Out + (size_t)batch * M * N;
  const int tx = tid & 15;
  const int ty = tid >> 4;
  const int a_row = tid >> 1;          // 0..127
  const int a_k = (tid & 1) * 8;       // 0 or 8
  const int b_row = tid >> 4;          // 0..15
  const int b_col = (tid & 15) * 8;    // 0..120

  float acc[8][8] = {};

  for (int k0 = 0; k0 < K; k0 += 16) {
    const float* wp = &W[(size_t)(bm + a_row) * K + k0 + a_k];
    float4 av0 = *(const float4*)(wp);
    float4 av1 = *(const float4*)(wp + 4);
    const float* xp = &Xb[(size_t)(k0 + b_row) * N + bn + b_col];
    float4 bv0 = *(const float4*)(xp);
    float4 bv1 = *(const float4*)(xp + 4);
    __syncthreads();  // prior iteration finished reading LDS
    As[a_k + 0][a_row] = av0.x;
    As[a_k + 1][a_row] = av0.y;
    As[a_k + 2][a_row] = av0.z;
    As[a_k + 3][a_row] = av0.w;
    As[a_k + 4][a_row] = av1.x;
    As[a_k + 5][a_row] = av1.y;
    As[a_k + 6][a_row] = av1.z;
    As[a_k + 7][a_row] = av1.w;
    *(float4*)&Bs[b_row][b_col] = bv0;
    *(float4*)&Bs[b_row][b_col + 4] = bv1;
    __syncthreads();
#pragma unroll
    for (int kk = 0; kk < 16; ++kk) {
      float ar[8], br[8];
      *(float4*)&ar[0] = *(const float4*)&As[kk][ty * 8];
      *(float4*)&ar[4] = *(const float4*)&As[kk][ty * 8 + 4];
      *(float4*)&br[0] = *(const float4*)&Bs[kk][tx * 8];
      *(float4*)&br[4] = *(const float4*)&Bs[kk][tx * 8 + 4];
#pragma unroll
      for (int i = 0; i < 8; ++i)
#pragma unroll
        for (int j = 0; j < 8; ++j) acc[i][j] += ar[i] * br[j];
    }
  }
#pragma unroll
  for (int i = 0; i < 8; ++i) {
    const int m = bm + ty * 8 + i;
    const float bi = bias[m];
    float4 o0, o1;
    o0.x = acc[i][0] + bi; o0.y = acc[i][1] + bi;
    o0.z = acc[i][2] + bi; o0.w = acc[i][3] + bi;
    o1.x = acc[i][4] + bi; o1.y = acc[i][5] + bi;
    o1.z = acc[i][6] + bi; o1.w = acc[i][7] + bi;
    *(float4*)&Ob[(size_t)m * N + bn + tx * 8] = o0;
    *(float4*)&Ob[(size_t)m * N + bn + tx * 8 + 4] = o1;
  }
}

// ------------------------- Fused attention ---------------------------------
// qkv layout: [b][o][l], o in [0,1536). Head h: q rows h*192+0..63,
// k rows h*192+64..127, v rows h*192+128..191.  (from the (B,3C,L)->
// (B*NH, 3ch, L) reshape!)
// One block = one (b,h) head x 64-wide t-tile. Online softmax over s-tiles.
// scale^2 = 1/sqrt(ch) = 1/8 folded into q at load.
__global__ __launch_bounds__(256) void attn_kernel(
    const float* __restrict__ qkv, float* __restrict__ a_out) {
  __shared__ __align__(16) float qs[64][TP];   // [ch][t], pre-scaled
  __shared__ __align__(16) float ks[64][TP];   // [ch][s]
  __shared__ __align__(16) float vst[64][TP];  // [s][ch]  (transposed)
  __shared__ __align__(16) float Ps[64][TP];   // [s][t] scores -> probs
  __shared__ float mrow[64], lrow[64], arow[64];

  const int tid = threadIdx.x;
  const int bh = blockIdx.y;
  const int b = bh >> 3;
  const int h = bh & 7;
  const int t0 = blockIdx.x * 64;
  const float* base = qkv + ((size_t)b * 1536 + (size_t)h * 192) * 1024;

#pragma unroll
  for (int r = 0; r < 4; ++r) {
    const int f4 = tid + 256 * r;       // 0..1023 float4s
    const int ch = f4 >> 4;             // 0..63
    const int off = (f4 & 15) << 2;     // 0..60
    float4 v = *(const float4*)&base[(size_t)ch * 1024 + t0 + off];
    v.x *= 0.125f; v.y *= 0.125f; v.z *= 0.125f; v.w *= 0.125f;
    *(float4*)&qs[ch][off] = v;
  }
  if (tid < 64) {
    mrow[tid] = -1e30f;
    lrow[tid] = 0.f;
  }

  const int tx = tid & 15;
  const int ty = tid >> 4;
  float acc[4][4] = {};  // O[c=ty*4+i][t=tx*4+j]

  for (int s0 = 0; s0 < 1024; s0 += 64) {
#pragma unroll
    for (int r = 0; r < 4; ++r) {
      const int f4 = tid + 256 * r;
      const int ch = f4 >> 4;
      const int off = (f4 & 15) << 2;
      float4 kv = *(const float4*)&base[(size_t)(64 + ch) * 1024 + s0 + off];
      *(float4*)&ks[ch][off] = kv;
      float4 vv = *(const float4*)&base[(size_t)(128 + ch) * 1024 + s0 + off];
      vst[off + 0][ch] = vv.x;
      vst[off + 1][ch] = vv.y;
      vst[off + 2][ch] = vv.z;
      vst[off + 3][ch] = vv.w;
    }
    __syncthreads();

    // scores S[s][t] = sum_ch k[ch][s] * q_scaled[ch][t]
    float sacc[4][4] = {};
    for (int ch = 0; ch < 64; ++ch) {
      float kr[4], qr[4];
      *(float4*)kr = *(const float4*)&ks[ch][ty * 4];
      *(float4*)qr = *(const float4*)&qs[ch][tx * 4];
#pragma unroll
      for (int i = 0; i < 4; ++i)
#pragma unroll
        for (int j = 0; j < 4; ++j) sacc[i][j] += kr[i] * qr[j];
    }
#pragma unroll
    for (int i = 0; i < 4; ++i) {
      float4 o;
      o.x = sacc[i][0]; o.y = sacc[i][1]; o.z = sacc[i][2]; o.w = sacc[i][3];
      *(float4*)&Ps[ty * 4 + i][tx * 4] = o;
    }
    __syncthreads();

    // online softmax (over s) per t-column; one thread per t
    if (tid < 64) {
      const int t = tid;
      const float mold = mrow[t];
      float mx = mold;
      for (int s = 0; s < 64; ++s) mx = fmaxf(mx, Ps[s][t]);
      const float al = __expf(mold - mx);
      float sum = 0.f;
      for (int s = 0; s < 64; ++s) {
        const float p = __expf(Ps[s][t] - mx);
        Ps[s][t] = p;
        sum += p;
      }
      mrow[t] = mx;
      lrow[t] = lrow[t] * al + sum;
      arow[t] = al;
    }
    __syncthreads();

    // O = O*alpha + V^T P
    float al[4];
#pragma unroll
    for (int j = 0; j < 4; ++j) al[j] = arow[tx * 4 + j];
#pragma unroll
    for (int i = 0; i < 4; ++i)
#pragma unroll
      for (int j = 0; j < 4; ++j) acc[i][j] *= al[j];
    for (int s = 0; s < 64; ++s) {
      float vr[4], pr[4];
      *(float4*)vr = *(const float4*)&vst[s][ty * 4];
      *(float4*)pr = *(const float4*)&Ps[s][tx * 4];
#pragma unroll
      for (int i = 0; i < 4; ++i)
#pragma unroll
        for (int j = 0; j < 4; ++j) acc[i][j] += vr[i] * pr[j];
    }
    __syncthreads();  // before next tile overwrites ks/vst/Ps
  }

  float linv[4];
#pragma unroll
  for (int j = 0; j < 4; ++j) linv[j] = 1.f / lrow[tx * 4 + j];
#pragma unroll
  for (int i = 0; i < 4; ++i) {
    const int c = ty * 4 + i;
    float4 o;
    o.x = acc[i][0] * linv[0];
    o.y = acc[i][1] * linv[1];
    o.z = acc[i][2] * linv[2];
    o.w = acc[i][3] * linv[3];
    *(float4*)&a_out[((size_t)b * 512 + h * 64 + c) * 1024 + t0 + tx * 4] = o;
  }
}

// ---------------------------------------------------------------------------
extern "C" void kernel_launch(void* const* d_in, const int* in_sizes, int n_in,
                              void* d_out, int out_size, void* d_ws,
                              size_t ws_size, hipStream_t stream) {
  const float* x = (const float*)d_in[0];
  const float* norm_w = (const float*)d_in[1];
  const float* norm_b = (const float*)d_in[2];
  const float* w_qkv = (const float*)d_in[3];
  const float* b_qkv = (const float*)d_in[4];
  const float* w_proj = (const float*)d_in[5];
  const float* b_proj = (const float*)d_in[6];
  float* out = (float*)d_out;

  // workspace: h (16*512*1024 f32 = 33.5MB), qkv (16*1536*1024 f32 = 100.7MB)
  // attention output `a` reuses the h region (h is dead after QKV GEMM).
  float* h = (float*)d_ws;
  float* qkv = h + (size_t)16 * 512 * 1024;
  float* a = h;

  hipLaunchKernelGGL(gn_kernel, dim3(512), dim3(256), 0, stream,
                     x, norm_w, norm_b, h);
  hipLaunchKernelGGL(sgemm_bias, dim3(8, 12, 16), dim3(256), 0, stream,
                     w_qkv, h, b_qkv, qkv, 1536, 512, 1024);
  hipLaunchKernelGGL(attn_kernel, dim3(16, 128), dim3(256), 0, stream,
                     qkv, a);
  hipLaunchKernelGGL(sgemm_bias, dim3(8, 4, 16), dim3(256), 0, stream,
                     w_proj, a, b_proj, out, 512, 512, 1024);
}

// Round 2
// 658.476 us; speedup vs baseline: 1.5791x; 1.5791x over previous
//
#include <hip/hip_runtime.h>
#include <math.h>

// ---------------------------------------------------------------------------
// AttentionBlock: GroupNorm(32) -> QKV proj -> MHA(8 heads) -> out proj
// B=16, C=512, L=1024, group=16ch, head ch=64.
// Round 2: attention rewritten with bf16 MFMA (flash-style, online softmax).
// GN + SGEMMs still fp32 (next round).
// ---------------------------------------------------------------------------

typedef __attribute__((ext_vector_type(8))) short bf16x8;
typedef __attribute__((ext_vector_type(4))) float f32x4;

__device__ inline unsigned short f2bf(float f) {
  unsigned u = __float_as_uint(f);
  return (unsigned short)((u + 0x7fffu + ((u >> 16) & 1u)) >> 16);
}

// ------------------------- GroupNorm ---------------------------------------
__global__ __launch_bounds__(256) void gn_kernel(
    const float* __restrict__ x, const float* __restrict__ gw,
    const float* __restrict__ gb, float* __restrict__ h) {
  const int b = blockIdx.x >> 5;
  const int g = blockIdx.x & 31;
  const size_t base = ((size_t)(b * 512 + g * 16)) * 1024;
  const float4* xp = (const float4*)(x + base);
  float4* hp = (float4*)(h + base);
  const int tid = threadIdx.x;

  float4 vals[16];
  float s = 0.f, sq = 0.f;
#pragma unroll
  for (int r = 0; r < 16; ++r) {
    float4 v = xp[tid + 256 * r];
    vals[r] = v;
    s += v.x + v.y + v.z + v.w;
    sq += v.x * v.x + v.y * v.y + v.z * v.z + v.w * v.w;
  }
  __shared__ float rs[256];
  __shared__ float rq[256];
  rs[tid] = s;
  rq[tid] = sq;
  __syncthreads();
  for (int off = 128; off > 0; off >>= 1) {
    if (tid < off) {
      rs[tid] += rs[tid + off];
      rq[tid] += rq[tid + off];
    }
    __syncthreads();
  }
  const float mean = rs[0] * (1.f / 16384.f);
  const float var = rq[0] * (1.f / 16384.f) - mean * mean;
  const float rinv = rsqrtf(var + 1e-5f);
#pragma unroll
  for (int r = 0; r < 16; ++r) {
    const int c = g * 16 + r;
    const float wc = gw[c] * rinv;
    const float bc = gb[c] - mean * wc;
    float4 v = vals[r];
    v.x = v.x * wc + bc;
    v.y = v.y * wc + bc;
    v.z = v.z * wc + bc;
    v.w = v.w * wc + bc;
    hp[tid + 256 * r] = v;
  }
}

// ------------------------- SGEMM + bias (fp32) ------------------------------
__global__ __launch_bounds__(256) void sgemm_bias(
    const float* __restrict__ W, const float* __restrict__ X,
    const float* __restrict__ bias, float* __restrict__ Out,
    int M, int K, int N) {
  __shared__ __align__(16) float As[16][132];
  __shared__ __align__(16) float Bs[16][132];
  const int tid = threadIdx.x;
  const int bn = blockIdx.x * 128;
  const int bm = blockIdx.y * 128;
  const int batch = blockIdx.z;
  const float* Xb = X + (size_t)batch * K * N;
  float* Ob = Out + (size_t)batch * M * N;
  const int tx = tid & 15;
  const int ty = tid >> 4;
  const int a_row = tid >> 1;
  const int a_k = (tid & 1) * 8;
  const int b_row = tid >> 4;
  const int b_col = (tid & 15) * 8;

  float acc[8][8] = {};

  for (int k0 = 0; k0 < K; k0 += 16) {
    const float* wp = &W[(size_t)(bm + a_row) * K + k0 + a_k];
    float4 av0 = *(const float4*)(wp);
    float4 av1 = *(const float4*)(wp + 4);
    const float* xp = &Xb[(size_t)(k0 + b_row) * N + bn + b_col];
    float4 bv0 = *(const float4*)(xp);
    float4 bv1 = *(const float4*)(xp + 4);
    __syncthreads();
    As[a_k + 0][a_row] = av0.x;
    As[a_k + 1][a_row] = av0.y;
    As[a_k + 2][a_row] = av0.z;
    As[a_k + 3][a_row] = av0.w;
    As[a_k + 4][a_row] = av1.x;
    As[a_k + 5][a_row] = av1.y;
    As[a_k + 6][a_row] = av1.z;
    As[a_k + 7][a_row] = av1.w;
    *(float4*)&Bs[b_row][b_col] = bv0;
    *(float4*)&Bs[b_row][b_col + 4] = bv1;
    __syncthreads();
#pragma unroll
    for (int kk = 0; kk < 16; ++kk) {
      float ar[8], br[8];
      *(float4*)&ar[0] = *(const float4*)&As[kk][ty * 8];
      *(float4*)&ar[4] = *(const float4*)&As[kk][ty * 8 + 4];
      *(float4*)&br[0] = *(const float4*)&Bs[kk][tx * 8];
      *(float4*)&br[4] = *(const float4*)&Bs[kk][tx * 8 + 4];
#pragma unroll
      for (int i = 0; i < 8; ++i)
#pragma unroll
        for (int j = 0; j < 8; ++j) acc[i][j] += ar[i] * br[j];
    }
  }
#pragma unroll
  for (int i = 0; i < 8; ++i) {
    const int m = bm + ty * 8 + i;
    const float bi = bias[m];
    float4 o0, o1;
    o0.x = acc[i][0] + bi; o0.y = acc[i][1] + bi;
    o0.z = acc[i][2] + bi; o0.w = acc[i][3] + bi;
    o1.x = acc[i][4] + bi; o1.y = acc[i][5] + bi;
    o1.z = acc[i][6] + bi; o1.w = acc[i][7] + bi;
    *(float4*)&Ob[(size_t)m * N + bn + tx * 8] = o0;
    *(float4*)&Ob[(size_t)m * N + bn + tx * 8 + 4] = o1;
  }
}

// ------------------------- MFMA flash attention -----------------------------
// qkv layout: [b][o][l]; head h: q rows h*192+0..63, k +64..127, v +128..191.
// Block = (b,h) x 64-wide t-tile, 4 waves. s-loop over 16 tiles of 64.
// S[t][s] = sum_ch Qs[t][ch]*K[ch][s] via mfma(A=Q^T, B=K) — Q^T in LDS [t][ch],
// K^T in LDS [s][ch] (both give contiguous b128 frag reads).
// O[ch][t] += V[ch][s]*P[s][t] via mfma(A=V [ch][s], B=P [s][t]).
#define LQ 72  // qs/ks/vs row stride (bf16 elems); 144B rows keep b128 align
#define LP 68  // ps row stride; 136B rows, b64-aligned, better bank spread

__global__ __launch_bounds__(256, 4) void attn_mfma(
    const float* __restrict__ qkv, float* __restrict__ a_out) {
  __shared__ __align__(16) unsigned short qs[64 * LQ];  // [t][ch] prescaled
  __shared__ __align__(16) unsigned short ks[64 * LQ];  // [s][ch]
  __shared__ __align__(16) unsigned short vs[64 * LQ];  // [ch][s]
  __shared__ __align__(16) unsigned short ps[64 * LP];  // [s][t]
  __shared__ float alpha_s[64];

  const int tid = threadIdx.x;
  const int w = tid >> 6;
  const int lane = tid & 63;
  const int lx = lane & 15;
  const int quad = lane >> 4;
  const int bh = blockIdx.y;
  const int b = bh >> 3;
  const int h = bh & 7;
  const int t0 = blockIdx.x * 64;
  const float* qb = qkv + ((size_t)b * 1536 + (size_t)h * 192) * 1024;
  const float* kb = qb + 64 * 1024;
  const float* vb = qb + 128 * 1024;

  // ---- stage Q transposed + prescaled (once) ----
#pragma unroll
  for (int r = 0; r < 4; ++r) {
    int f4 = tid + 256 * r;
    int ch = f4 >> 4;
    int off = (f4 & 15) << 2;
    float4 v = *(const float4*)&qb[(size_t)ch * 1024 + t0 + off];
    qs[(off + 0) * LQ + ch] = f2bf(v.x * 0.125f);
    qs[(off + 1) * LQ + ch] = f2bf(v.y * 0.125f);
    qs[(off + 2) * LQ + ch] = f2bf(v.z * 0.125f);
    qs[(off + 3) * LQ + ch] = f2bf(v.w * 0.125f);
  }
  __syncthreads();
  // Q A-frags: A[m=t=w*16+lx][k=ch=kblk*32+quad*8+j]
  const bf16x8 qf0 = *(const bf16x8*)&qs[(w * 16 + lx) * LQ + quad * 8];
  const bf16x8 qf1 = *(const bf16x8*)&qs[(w * 16 + lx) * LQ + 32 + quad * 8];

  float m_r[4] = {-1e30f, -1e30f, -1e30f, -1e30f};
  float l_r[4] = {0.f, 0.f, 0.f, 0.f};
  f32x4 oacc[4];
#pragma unroll
  for (int mt = 0; mt < 4; ++mt) oacc[mt] = (f32x4){0.f, 0.f, 0.f, 0.f};

  for (int s0 = 0; s0 < 1024; s0 += 64) {
    __syncthreads();  // prior iteration's LDS reads complete
    // ---- stage K transposed: thread owns s=tid&63, 4 ch-quads ----
    {
      const int s = tid & 63;
#pragma unroll
      for (int r = 0; r < 4; ++r) {
        const int cb = ((tid >> 6) + 4 * r) * 4;
        unsigned short t4[4];
#pragma unroll
        for (int i = 0; i < 4; ++i)
          t4[i] = f2bf(kb[(size_t)(cb + i) * 1024 + s0 + s]);
        *(uint2*)&ks[s * LQ + cb] =
            make_uint2((unsigned)t4[0] | ((unsigned)t4[1] << 16),
                       (unsigned)t4[2] | ((unsigned)t4[3] << 16));
      }
    }
    // ---- stage V natural [ch][s] ----
#pragma unroll
    for (int r = 0; r < 4; ++r) {
      int f4 = tid + 256 * r;
      int ch = f4 >> 4;
      int off = (f4 & 15) << 2;
      float4 v = *(const float4*)&vb[(size_t)ch * 1024 + s0 + off];
      *(uint2*)&vs[ch * LQ + off] =
          make_uint2((unsigned)f2bf(v.x) | ((unsigned)f2bf(v.y) << 16),
                     (unsigned)f2bf(v.z) | ((unsigned)f2bf(v.w) << 16));
    }
    __syncthreads();

    // ---- S tiles: wave w owns t rows [w*16, w*16+16), all 64 s ----
    f32x4 sf[4];
#pragma unroll
    for (int n = 0; n < 4; ++n) {
      bf16x8 k0 = *(const bf16x8*)&ks[(n * 16 + lx) * LQ + quad * 8];
      bf16x8 k1 = *(const bf16x8*)&ks[(n * 16 + lx) * LQ + 32 + quad * 8];
      f32x4 z = {0.f, 0.f, 0.f, 0.f};
      z = __builtin_amdgcn_mfma_f32_16x16x32_bf16(qf0, k0, z, 0, 0, 0);
      sf[n] = __builtin_amdgcn_mfma_f32_16x16x32_bf16(qf1, k1, z, 0, 0, 0);
    }

    // ---- online softmax: row t = w*16+quad*4+i, col s = n*16+lx ----
    float mx[4];
#pragma unroll
    for (int i = 0; i < 4; ++i)
      mx[i] = fmaxf(fmaxf(sf[0][i], sf[1][i]), fmaxf(sf[2][i], sf[3][i]));
#pragma unroll
    for (int d = 1; d < 16; d <<= 1)
#pragma unroll
      for (int i = 0; i < 4; ++i) mx[i] = fmaxf(mx[i], __shfl_xor(mx[i], d));
    float alpha[4], sum[4];
#pragma unroll
    for (int i = 0; i < 4; ++i) {
      float nm = fmaxf(m_r[i], mx[i]);
      alpha[i] = __expf(m_r[i] - nm);
      m_r[i] = nm;
      sum[i] = 0.f;
    }
#pragma unroll
    for (int n = 0; n < 4; ++n) {
      unsigned short pb[4];
#pragma unroll
      for (int i = 0; i < 4; ++i) {
        float p = __expf(sf[n][i] - m_r[i]);
        sum[i] += p;
        pb[i] = f2bf(p);
      }
      // P[s=n*16+lx][t=w*16+quad*4 + 0..3] as one b64 write
      *(uint2*)&ps[(n * 16 + lx) * LP + w * 16 + quad * 4] =
          make_uint2((unsigned)pb[0] | ((unsigned)pb[1] << 16),
                     (unsigned)pb[2] | ((unsigned)pb[3] << 16));
    }
#pragma unroll
    for (int d = 1; d < 16; d <<= 1)
#pragma unroll
      for (int i = 0; i < 4; ++i) sum[i] += __shfl_xor(sum[i], d);
#pragma unroll
    for (int i = 0; i < 4; ++i) l_r[i] = l_r[i] * alpha[i] + sum[i];
    if (lx == 0) {
#pragma unroll
      for (int i = 0; i < 4; ++i) alpha_s[w * 16 + quad * 4 + i] = alpha[i];
    }
    __syncthreads();

    // ---- rescale O, then O[ch][t] += V P ----
    const float av = alpha_s[w * 16 + lx];
#pragma unroll
    for (int mt = 0; mt < 4; ++mt)
#pragma unroll
      for (int i = 0; i < 4; ++i) oacc[mt][i] *= av;
#pragma unroll
    for (int kbi = 0; kbi < 2; ++kbi) {
      bf16x8 pf;
#pragma unroll
      for (int j = 0; j < 8; ++j)
        pf[j] = (short)ps[(kbi * 32 + quad * 8 + j) * LP + w * 16 + lx];
#pragma unroll
      for (int mt = 0; mt < 4; ++mt) {
        bf16x8 vf =
            *(const bf16x8*)&vs[(mt * 16 + lx) * LQ + kbi * 32 + quad * 8];
        oacc[mt] = __builtin_amdgcn_mfma_f32_16x16x32_bf16(vf, pf, oacc[mt],
                                                           0, 0, 0);
      }
    }
  }

  // ---- epilogue: normalize by l, store ----
  __syncthreads();
  if (lx == 0) {
#pragma unroll
    for (int i = 0; i < 4; ++i) alpha_s[w * 16 + quad * 4 + i] = l_r[i];
  }
  __syncthreads();
  const float linv = 1.f / alpha_s[w * 16 + lx];
  float* obase = a_out + ((size_t)b * 512 + h * 64) * 1024 + t0 + w * 16 + lx;
#pragma unroll
  for (int mt = 0; mt < 4; ++mt)
#pragma unroll
    for (int i = 0; i < 4; ++i)
      obase[(size_t)(mt * 16 + quad * 4 + i) * 1024] = oacc[mt][i] * linv;
}

// ---------------------------------------------------------------------------
extern "C" void kernel_launch(void* const* d_in, const int* in_sizes, int n_in,
                              void* d_out, int out_size, void* d_ws,
                              size_t ws_size, hipStream_t stream) {
  const float* x = (const float*)d_in[0];
  const float* norm_w = (const float*)d_in[1];
  const float* norm_b = (const float*)d_in[2];
  const float* w_qkv = (const float*)d_in[3];
  const float* b_qkv = (const float*)d_in[4];
  const float* w_proj = (const float*)d_in[5];
  const float* b_proj = (const float*)d_in[6];
  float* out = (float*)d_out;

  float* h = (float*)d_ws;
  float* qkv = h + (size_t)16 * 512 * 1024;
  float* a = h;

  hipLaunchKernelGGL(gn_kernel, dim3(512), dim3(256), 0, stream,
                     x, norm_w, norm_b, h);
  hipLaunchKernelGGL(sgemm_bias, dim3(8, 12, 16), dim3(256), 0, stream,
                     w_qkv, h, b_qkv, qkv, 1536, 512, 1024);
  hipLaunchKernelGGL(attn_mfma, dim3(16, 128), dim3(256), 0, stream,
                     qkv, a);
  hipLaunchKernelGGL(sgemm_bias, dim3(8, 4, 16), dim3(256), 0, stream,
                     w_proj, a, b_proj, out, 512, 512, 1024);
}

// Round 3
// 301.852 us; speedup vs baseline: 3.4446x; 2.1815x over previous
//
#include <hip/hip_runtime.h>
#include <math.h>

// ---------------------------------------------------------------------------
// AttentionBlock: GroupNorm(32) -> QKV proj -> MHA(8 heads) -> out proj
// B=16, C=512, L=1024, group=16ch, head ch=64.
// Round 3: full fp16-MFMA pipeline. All intermediates fp16, k-contiguous:
//   hT [b][l][c] -> qkvT [b][l][o] -> aT [b][l][c] -> out [b][c][l] (fp32)
// ---------------------------------------------------------------------------

typedef _Float16 f16x8 __attribute__((ext_vector_type(8)));
typedef _Float16 f16x4 __attribute__((ext_vector_type(4)));
typedef float f32x4 __attribute__((ext_vector_type(4)));

// ------------------------- weight fp32 -> fp16 ------------------------------
__global__ __launch_bounds__(256) void f32_to_f16(
    const float* __restrict__ src, _Float16* __restrict__ dst, int n4) {
  int i = blockIdx.x * 256 + threadIdx.x;
  if (i < n4) {
    float4 v = ((const float4*)src)[i];
    f16x4 o = {(_Float16)v.x, (_Float16)v.y, (_Float16)v.z, (_Float16)v.w};
    *(f16x4*)&dst[(size_t)i * 4] = o;
  }
}

// ------------------------- GroupNorm (writes hT [b][l][c] fp16) -------------
__global__ __launch_bounds__(256) void gn_kernel(
    const float* __restrict__ x, const float* __restrict__ gw,
    const float* __restrict__ gb, _Float16* __restrict__ hT) {
  const int b = blockIdx.x >> 5;
  const int g = blockIdx.x & 31;
  const size_t base = ((size_t)(b * 512 + g * 16)) * 1024;
  const float4* xp = (const float4*)(x + base);
  const int tid = threadIdx.x;

  float4 vals[16];
  float s = 0.f, sq = 0.f;
#pragma unroll
  for (int r = 0; r < 16; ++r) {
    float4 v = xp[tid + 256 * r];  // channel g*16+r, l = tid*4..tid*4+3
    vals[r] = v;
    s += v.x + v.y + v.z + v.w;
    sq += v.x * v.x + v.y * v.y + v.z * v.z + v.w * v.w;
  }
  __shared__ float rs[256];
  __shared__ float rq[256];
  rs[tid] = s;
  rq[tid] = sq;
  __syncthreads();
  for (int off = 128; off > 0; off >>= 1) {
    if (tid < off) {
      rs[tid] += rs[tid + off];
      rq[tid] += rq[tid + off];
    }
    __syncthreads();
  }
  const float mean = rs[0] * (1.f / 16384.f);
  const float var = rq[0] * (1.f / 16384.f) - mean * mean;
  const float rinv = rsqrtf(var + 1e-5f);
#pragma unroll
  for (int r = 0; r < 16; ++r) {
    const int c = g * 16 + r;
    const float wc = gw[c] * rinv;
    const float bc = gb[c] - mean * wc;
    vals[r].x = vals[r].x * wc + bc;
    vals[r].y = vals[r].y * wc + bc;
    vals[r].z = vals[r].z * wc + bc;
    vals[r].w = vals[r].w * wc + bc;
  }
  // transposed store: hT[b][l=tid*4+li][g*16 .. g*16+15], 2x 16B per row
  _Float16* hb = hT + ((size_t)b * 1024 + tid * 4) * 512 + g * 16;
#pragma unroll
  for (int li = 0; li < 4; ++li) {
    f16x8 o0, o1;
#pragma unroll
    for (int r = 0; r < 8; ++r) {
      float v0 = li == 0 ? vals[r].x : li == 1 ? vals[r].y
                 : li == 2 ? vals[r].z : vals[r].w;
      float v1 = li == 0 ? vals[8 + r].x : li == 1 ? vals[8 + r].y
                 : li == 2 ? vals[8 + r].z : vals[8 + r].w;
      o0[r] = (_Float16)v0;
      o1[r] = (_Float16)v1;
    }
    *(f16x8*)(hb + (size_t)li * 512) = o0;
    *(f16x8*)(hb + (size_t)li * 512 + 8) = o1;
  }
}

// ------------------------- fp16 MFMA GEMM -----------------------------------
// C[m][n] = sum_k A[m][k]*B[n][k] (+bias), stored TRANSPOSED: Out[n][m].
// A: [M][K] row-major fp16 (k contig). B: [N][K] row-major fp16 (k contig).
// 128x128 tile, BK=32, 256 thr = 4 waves (2x2 of 64x64).
template <typename OutT, bool BIAS_ON_M>
__global__ __launch_bounds__(256) void gemm_tn(
    const _Float16* __restrict__ A, const _Float16* __restrict__ B,
    const float* __restrict__ bias, OutT* __restrict__ Out,
    int M, int N, int K, long sA, long sB) {
  __shared__ __align__(16) _Float16 As[128 * 32];
  __shared__ __align__(16) _Float16 Bs[128 * 32];
  const int tid = threadIdx.x;
  const int w = tid >> 6, lane = tid & 63;
  const int lx = lane & 15, quad = lane >> 4;
  const int wm = w >> 1, wn = w & 1;
  const int bn = blockIdx.x * 128, bm = blockIdx.y * 128;
  const int z = blockIdx.z;
  // staging: thread owns row = tid>>1 (0..127), half = (tid&1)*16 of BK=32
  const int srow = tid >> 1;
  const int shalf = (tid & 1) * 16;
  const _Float16* Ag = A + (size_t)z * sA + (size_t)(bm + srow) * K + shalf;
  const _Float16* Bg = B + (size_t)z * sB + (size_t)(bn + srow) * K + shalf;
  _Float16* Asw = &As[srow * 32 + shalf];
  _Float16* Bsw = &Bs[srow * 32 + shalf];

  f32x4 acc[4][4];
#pragma unroll
  for (int i = 0; i < 4; ++i)
#pragma unroll
    for (int j = 0; j < 4; ++j) acc[i][j] = (f32x4){0.f, 0.f, 0.f, 0.f};

  for (int k0 = 0; k0 < K; k0 += 32) {
    f16x8 a0 = *(const f16x8*)(Ag + k0);
    f16x8 a1 = *(const f16x8*)(Ag + k0 + 8);
    f16x8 b0 = *(const f16x8*)(Bg + k0);
    f16x8 b1 = *(const f16x8*)(Bg + k0 + 8);
    __syncthreads();  // prior iteration's LDS reads done
    *(f16x8*)Asw = a0;
    *(f16x8*)(Asw + 8) = a1;
    *(f16x8*)Bsw = b0;
    *(f16x8*)(Bsw + 8) = b1;
    __syncthreads();
    f16x8 af[4], bf[4];
#pragma unroll
    for (int mt = 0; mt < 4; ++mt)
      af[mt] = *(const f16x8*)&As[(wm * 64 + mt * 16 + lx) * 32 + quad * 8];
#pragma unroll
    for (int nt = 0; nt < 4; ++nt)
      bf[nt] = *(const f16x8*)&Bs[(wn * 64 + nt * 16 + lx) * 32 + quad * 8];
#pragma unroll
    for (int mt = 0; mt < 4; ++mt)
#pragma unroll
      for (int nt = 0; nt < 4; ++nt)
        acc[mt][nt] = __builtin_amdgcn_mfma_f32_16x16x32_f16(
            af[mt], bf[nt], acc[mt][nt], 0, 0, 0);
  }

  OutT* Ob = Out + (size_t)z * M * N;
#pragma unroll
  for (int mt = 0; mt < 4; ++mt) {
    const int m0 = bm + wm * 64 + mt * 16 + quad * 4;
    float bm4[4];
#pragma unroll
    for (int i = 0; i < 4; ++i) bm4[i] = BIAS_ON_M ? bias[m0 + i] : 0.f;
#pragma unroll
    for (int nt = 0; nt < 4; ++nt) {
      const int n = bn + wn * 64 + nt * 16 + lx;
      const float bn1 = BIAS_ON_M ? 0.f : bias[n];
      float v[4];
#pragma unroll
      for (int i = 0; i < 4; ++i)
        v[i] = acc[mt][nt][i] + (BIAS_ON_M ? bm4[i] : bn1);
      if constexpr (sizeof(OutT) == 2) {
        f16x4 o = {(_Float16)v[0], (_Float16)v[1], (_Float16)v[2],
                   (_Float16)v[3]};
        *(f16x4*)((_Float16*)Ob + (size_t)n * M + m0) = o;
      } else {
        float4 o = {v[0], v[1], v[2], v[3]};
        *(float4*)((float*)Ob + (size_t)n * M + m0) = o;
      }
    }
  }
}

// ------------------------- fp16 MFMA flash attention ------------------------
// qkvT layout: [b][l][o], o = h*192 + {0..63 q, 64..127 k, 128..191 v}.
// Block = (b,h) x 64-wide t-tile, 4 waves, s-loop 16 tiles of 64.
// Writes aT [b][l][c] fp16.
#define LQ 72
#define LP 68

__global__ __launch_bounds__(256) void attn_mfma(
    const _Float16* __restrict__ qkvT, _Float16* __restrict__ aT) {
  __shared__ __align__(16) _Float16 qs[64 * LQ];  // [t][ch]
  __shared__ __align__(16) _Float16 ks[64 * LQ];  // [s][ch]
  __shared__ __align__(16) _Float16 vs[64 * LQ];  // [ch][s] (transposed)
  __shared__ __align__(16) _Float16 ps[64 * LP];  // [s][t]
  __shared__ float alpha_s[64];

  const int tid = threadIdx.x;
  const int w = tid >> 6;
  const int lane = tid & 63;
  const int lx = lane & 15;
  const int quad = lane >> 4;
  const int bh = blockIdx.y;
  const int b = bh >> 3;
  const int h = bh & 7;
  const int t0 = blockIdx.x * 64;
  const _Float16* qb = qkvT + (size_t)b * 1024 * 1536 + h * 192;

  // ---- stage Q [t][ch]: direct copy, ch contiguous ----
  {
    const int t = tid >> 2, c = (tid & 3) * 16;
    const _Float16* g = qb + (size_t)(t0 + t) * 1536 + c;
    *(f16x8*)&qs[t * LQ + c] = *(const f16x8*)g;
    *(f16x8*)&qs[t * LQ + c + 8] = *(const f16x8*)(g + 8);
  }
  __syncthreads();
  const f16x8 qf0 = *(const f16x8*)&qs[(w * 16 + lx) * LQ + quad * 8];
  const f16x8 qf1 = *(const f16x8*)&qs[(w * 16 + lx) * LQ + 32 + quad * 8];

  float m_r[4] = {-1e30f, -1e30f, -1e30f, -1e30f};
  float l_r[4] = {0.f, 0.f, 0.f, 0.f};
  f32x4 oacc[4];
#pragma unroll
  for (int mt = 0; mt < 4; ++mt) oacc[mt] = (f32x4){0.f, 0.f, 0.f, 0.f};

  for (int s0 = 0; s0 < 1024; s0 += 64) {
    __syncthreads();
    // ---- K [s][ch]: direct copy ----
    {
      const int t = tid >> 2, c = (tid & 3) * 16;
      const _Float16* g = qb + (size_t)(s0 + t) * 1536 + 64 + c;
      *(f16x8*)&ks[t * LQ + c] = *(const f16x8*)g;
      *(f16x8*)&ks[t * LQ + c + 8] = *(const f16x8*)(g + 8);
    }
    // ---- V [ch][s]: transpose, s-pairs packed as b32 ----
    {
      const int s2 = (tid >> 3) * 2, c8 = (tid & 7) * 8;
      const _Float16* g = qb + (size_t)(s0 + s2) * 1536 + 128 + c8;
      f16x8 v0 = *(const f16x8*)g;
      f16x8 v1 = *(const f16x8*)(g + 1536);
#pragma unroll
      for (int i = 0; i < 8; ++i) {
        union { _Float16 hh[2]; unsigned u; } p;
        p.hh[0] = v0[i];
        p.hh[1] = v1[i];
        *(unsigned*)&vs[(c8 + i) * LQ + s2] = p.u;
      }
    }
    __syncthreads();

    // ---- S[t][s] via mfma: A=Q[t][ch], B=K[s][ch] ----
    f32x4 sf[4];
#pragma unroll
    for (int n = 0; n < 4; ++n) {
      f16x8 k0 = *(const f16x8*)&ks[(n * 16 + lx) * LQ + quad * 8];
      f16x8 k1 = *(const f16x8*)&ks[(n * 16 + lx) * LQ + 32 + quad * 8];
      f32x4 zz = {0.f, 0.f, 0.f, 0.f};
      zz = __builtin_amdgcn_mfma_f32_16x16x32_f16(qf0, k0, zz, 0, 0, 0);
      sf[n] = __builtin_amdgcn_mfma_f32_16x16x32_f16(qf1, k1, zz, 0, 0, 0);
#pragma unroll
      for (int i = 0; i < 4; ++i) sf[n][i] *= 0.125f;  // scale^2 = 1/sqrt(64)
    }

    // ---- online softmax: row t = w*16+quad*4+i, col s = n*16+lx ----
    float mx[4];
#pragma unroll
    for (int i = 0; i < 4; ++i)
      mx[i] = fmaxf(fmaxf(sf[0][i], sf[1][i]), fmaxf(sf[2][i], sf[3][i]));
#pragma unroll
    for (int d = 1; d < 16; d <<= 1)
#pragma unroll
      for (int i = 0; i < 4; ++i) mx[i] = fmaxf(mx[i], __shfl_xor(mx[i], d));
    float alpha[4], sum[4];
#pragma unroll
    for (int i = 0; i < 4; ++i) {
      float nm = fmaxf(m_r[i], mx[i]);
      alpha[i] = __expf(m_r[i] - nm);
      m_r[i] = nm;
      sum[i] = 0.f;
    }
#pragma unroll
    for (int n = 0; n < 4; ++n) {
      float p0 = __expf(sf[n][0] - m_r[0]);
      float p1 = __expf(sf[n][1] - m_r[1]);
      float p2 = __expf(sf[n][2] - m_r[2]);
      float p3 = __expf(sf[n][3] - m_r[3]);
      sum[0] += p0; sum[1] += p1; sum[2] += p2; sum[3] += p3;
      f16x4 pv = {(_Float16)p0, (_Float16)p1, (_Float16)p2, (_Float16)p3};
      *(f16x4*)&ps[(n * 16 + lx) * LP + w * 16 + quad * 4] = pv;
    }
#pragma unroll
    for (int d = 1; d < 16; d <<= 1)
#pragma unroll
      for (int i = 0; i < 4; ++i) sum[i] += __shfl_xor(sum[i], d);
#pragma unroll
    for (int i = 0; i < 4; ++i) l_r[i] = l_r[i] * alpha[i] + sum[i];
    if (lx == 0) {
#pragma unroll
      for (int i = 0; i < 4; ++i) alpha_s[w * 16 + quad * 4 + i] = alpha[i];
    }
    __syncthreads();

    // ---- O[ch][t] = O*alpha + V[ch][s] P[s][t] ----
    const float av = alpha_s[w * 16 + lx];
#pragma unroll
    for (int mt = 0; mt < 4; ++mt)
#pragma unroll
      for (int i = 0; i < 4; ++i) oacc[mt][i] *= av;
#pragma unroll
    for (int kbi = 0; kbi < 2; ++kbi) {
      f16x8 pf;
#pragma unroll
      for (int j = 0; j < 8; ++j)
        pf[j] = ps[(kbi * 32 + quad * 8 + j) * LP + w * 16 + lx];
#pragma unroll
      for (int mt = 0; mt < 4; ++mt) {
        f16x8 vf = *(const f16x8*)&vs[(mt * 16 + lx) * LQ + kbi * 32 + quad * 8];
        oacc[mt] = __builtin_amdgcn_mfma_f32_16x16x32_f16(vf, pf, oacc[mt],
                                                          0, 0, 0);
      }
    }
  }

  // ---- epilogue: aT[b][t][h*64+ch] = O/l ----
  __syncthreads();
  if (lx == 0) {
#pragma unroll
    for (int i = 0; i < 4; ++i) alpha_s[w * 16 + quad * 4 + i] = l_r[i];
  }
  __syncthreads();
  const float linv = 1.f / alpha_s[w * 16 + lx];
  _Float16* ob = aT + ((size_t)b * 1024 + t0 + w * 16 + lx) * 512 + h * 64;
#pragma unroll
  for (int mt = 0; mt < 4; ++mt) {
    f16x4 o = {(_Float16)(oacc[mt][0] * linv), (_Float16)(oacc[mt][1] * linv),
               (_Float16)(oacc[mt][2] * linv), (_Float16)(oacc[mt][3] * linv)};
    *(f16x4*)&ob[mt * 16 + quad * 4] = o;
  }
}

// ---------------------------------------------------------------------------
extern "C" void kernel_launch(void* const* d_in, const int* in_sizes, int n_in,
                              void* d_out, int out_size, void* d_ws,
                              size_t ws_size, hipStream_t stream) {
  const float* x = (const float*)d_in[0];
  const float* norm_w = (const float*)d_in[1];
  const float* norm_b = (const float*)d_in[2];
  const float* w_qkv = (const float*)d_in[3];
  const float* b_qkv = (const float*)d_in[4];
  const float* w_proj = (const float*)d_in[5];
  const float* b_proj = (const float*)d_in[6];
  float* out = (float*)d_out;

  // ws: hT (8.39M f16) | qkvT (25.2M) | wq (0.79M) | wp (0.26M); aT reuses hT
  _Float16* hT = (_Float16*)d_ws;
  _Float16* qkvT = hT + (size_t)16 * 1024 * 512;
  _Float16* wq = qkvT + (size_t)16 * 1024 * 1536;
  _Float16* wp = wq + (size_t)1536 * 512;
  _Float16* aT = hT;

  f32_to_f16<<<768, 256, 0, stream>>>(w_qkv, wq, 196608);
  f32_to_f16<<<256, 256, 0, stream>>>(w_proj, wp, 65536);
  gn_kernel<<<512, 256, 0, stream>>>(x, norm_w, norm_b, hT);
  // qkvT[b][l][o] = W_qkv x hT : A=wq [1536][512], B=hT [1024][512] batched
  gemm_tn<_Float16, true><<<dim3(8, 12, 16), 256, 0, stream>>>(
      wq, hT, b_qkv, qkvT, 1536, 1024, 512, 0L, 524288L);
  attn_mfma<<<dim3(16, 128), 256, 0, stream>>>(qkvT, aT);
  // out[b][c][l] = (aT x wp^T)^T : A=aT [1024][512] batched, B=wp [512][512]
  gemm_tn<float, false><<<dim3(4, 8, 16), 256, 0, stream>>>(
      aT, wp, b_proj, out, 1024, 512, 512, 524288L, 0L);
}

// Round 5
// 298.435 us; speedup vs baseline: 3.4841x; 1.0114x over previous
//
#include <hip/hip_runtime.h>
#include <math.h>

// ---------------------------------------------------------------------------
// AttentionBlock: GroupNorm(32) -> QKV proj -> MHA(8 heads) -> out proj
// B=16, C=512, L=1024, group=16ch, head ch=64.
// Round 5 (= R4 retry, builtin name fixed): attn restructured — S^T via
// mfma(A=K,B=Q) so P stays in REGISTERS (C-frag of K=32 mfma == B-frag of
// K=16 mfma); waves split s (flash-decode), cross-wave combine once per
// block. No P LDS, no alpha LDS, 2 barriers/tile.
// ---------------------------------------------------------------------------

typedef _Float16 f16x8 __attribute__((ext_vector_type(8)));
typedef _Float16 f16x4 __attribute__((ext_vector_type(4)));
typedef float f32x4 __attribute__((ext_vector_type(4)));

// NOTE: legacy K=16 fp16 MFMA builtin has NO underscore before f16.
#define MFMA_K16(A, B, C) __builtin_amdgcn_mfma_f32_16x16x16f16(A, B, C, 0, 0, 0)

// ------------------------- weight fp32 -> fp16 ------------------------------
__global__ __launch_bounds__(256) void f32_to_f16(
    const float* __restrict__ src, _Float16* __restrict__ dst, int n4) {
  int i = blockIdx.x * 256 + threadIdx.x;
  if (i < n4) {
    float4 v = ((const float4*)src)[i];
    f16x4 o = {(_Float16)v.x, (_Float16)v.y, (_Float16)v.z, (_Float16)v.w};
    *(f16x4*)&dst[(size_t)i * 4] = o;
  }
}

// ------------------------- GroupNorm (writes hT [b][l][c] fp16) -------------
__global__ __launch_bounds__(256) void gn_kernel(
    const float* __restrict__ x, const float* __restrict__ gw,
    const float* __restrict__ gb, _Float16* __restrict__ hT) {
  const int b = blockIdx.x >> 5;
  const int g = blockIdx.x & 31;
  const size_t base = ((size_t)(b * 512 + g * 16)) * 1024;
  const float4* xp = (const float4*)(x + base);
  const int tid = threadIdx.x;

  float4 vals[16];
  float s = 0.f, sq = 0.f;
#pragma unroll
  for (int r = 0; r < 16; ++r) {
    float4 v = xp[tid + 256 * r];
    vals[r] = v;
    s += v.x + v.y + v.z + v.w;
    sq += v.x * v.x + v.y * v.y + v.z * v.z + v.w * v.w;
  }
  __shared__ float rs[256];
  __shared__ float rq[256];
  rs[tid] = s;
  rq[tid] = sq;
  __syncthreads();
  for (int off = 128; off > 0; off >>= 1) {
    if (tid < off) {
      rs[tid] += rs[tid + off];
      rq[tid] += rq[tid + off];
    }
    __syncthreads();
  }
  const float mean = rs[0] * (1.f / 16384.f);
  const float var = rq[0] * (1.f / 16384.f) - mean * mean;
  const float rinv = rsqrtf(var + 1e-5f);
#pragma unroll
  for (int r = 0; r < 16; ++r) {
    const int c = g * 16 + r;
    const float wc = gw[c] * rinv;
    const float bc = gb[c] - mean * wc;
    vals[r].x = vals[r].x * wc + bc;
    vals[r].y = vals[r].y * wc + bc;
    vals[r].z = vals[r].z * wc + bc;
    vals[r].w = vals[r].w * wc + bc;
  }
  _Float16* hb = hT + ((size_t)b * 1024 + tid * 4) * 512 + g * 16;
#pragma unroll
  for (int li = 0; li < 4; ++li) {
    f16x8 o0, o1;
#pragma unroll
    for (int r = 0; r < 8; ++r) {
      float v0 = li == 0 ? vals[r].x : li == 1 ? vals[r].y
                 : li == 2 ? vals[r].z : vals[r].w;
      float v1 = li == 0 ? vals[8 + r].x : li == 1 ? vals[8 + r].y
                 : li == 2 ? vals[8 + r].z : vals[8 + r].w;
      o0[r] = (_Float16)v0;
      o1[r] = (_Float16)v1;
    }
    *(f16x8*)(hb + (size_t)li * 512) = o0;
    *(f16x8*)(hb + (size_t)li * 512 + 8) = o1;
  }
}

// ------------------------- fp16 MFMA GEMM (unchanged R3) --------------------
template <typename OutT, bool BIAS_ON_M>
__global__ __launch_bounds__(256) void gemm_tn(
    const _Float16* __restrict__ A, const _Float16* __restrict__ B,
    const float* __restrict__ bias, OutT* __restrict__ Out,
    int M, int N, int K, long sA, long sB) {
  __shared__ __align__(16) _Float16 As[128 * 32];
  __shared__ __align__(16) _Float16 Bs[128 * 32];
  const int tid = threadIdx.x;
  const int w = tid >> 6, lane = tid & 63;
  const int lx = lane & 15, quad = lane >> 4;
  const int wm = w >> 1, wn = w & 1;
  const int bn = blockIdx.x * 128, bm = blockIdx.y * 128;
  const int z = blockIdx.z;
  const int srow = tid >> 1;
  const int shalf = (tid & 1) * 16;
  const _Float16* Ag = A + (size_t)z * sA + (size_t)(bm + srow) * K + shalf;
  const _Float16* Bg = B + (size_t)z * sB + (size_t)(bn + srow) * K + shalf;
  _Float16* Asw = &As[srow * 32 + shalf];
  _Float16* Bsw = &Bs[srow * 32 + shalf];

  f32x4 acc[4][4];
#pragma unroll
  for (int i = 0; i < 4; ++i)
#pragma unroll
    for (int j = 0; j < 4; ++j) acc[i][j] = (f32x4){0.f, 0.f, 0.f, 0.f};

  for (int k0 = 0; k0 < K; k0 += 32) {
    f16x8 a0 = *(const f16x8*)(Ag + k0);
    f16x8 a1 = *(const f16x8*)(Ag + k0 + 8);
    f16x8 b0 = *(const f16x8*)(Bg + k0);
    f16x8 b1 = *(const f16x8*)(Bg + k0 + 8);
    __syncthreads();
    *(f16x8*)Asw = a0;
    *(f16x8*)(Asw + 8) = a1;
    *(f16x8*)Bsw = b0;
    *(f16x8*)(Bsw + 8) = b1;
    __syncthreads();
    f16x8 af[4], bf[4];
#pragma unroll
    for (int mt = 0; mt < 4; ++mt)
      af[mt] = *(const f16x8*)&As[(wm * 64 + mt * 16 + lx) * 32 + quad * 8];
#pragma unroll
    for (int nt = 0; nt < 4; ++nt)
      bf[nt] = *(const f16x8*)&Bs[(wn * 64 + nt * 16 + lx) * 32 + quad * 8];
#pragma unroll
    for (int mt = 0; mt < 4; ++mt)
#pragma unroll
      for (int nt = 0; nt < 4; ++nt)
        acc[mt][nt] = __builtin_amdgcn_mfma_f32_16x16x32_f16(
            af[mt], bf[nt], acc[mt][nt], 0, 0, 0);
  }

  OutT* Ob = Out + (size_t)z * M * N;
#pragma unroll
  for (int mt = 0; mt < 4; ++mt) {
    const int m0 = bm + wm * 64 + mt * 16 + quad * 4;
    float bm4[4];
#pragma unroll
    for (int i = 0; i < 4; ++i) bm4[i] = BIAS_ON_M ? bias[m0 + i] : 0.f;
#pragma unroll
    for (int nt = 0; nt < 4; ++nt) {
      const int n = bn + wn * 64 + nt * 16 + lx;
      const float bn1 = BIAS_ON_M ? 0.f : bias[n];
      float v[4];
#pragma unroll
      for (int i = 0; i < 4; ++i)
        v[i] = acc[mt][nt][i] + (BIAS_ON_M ? bm4[i] : bn1);
      if constexpr (sizeof(OutT) == 2) {
        f16x4 o = {(_Float16)v[0], (_Float16)v[1], (_Float16)v[2],
                   (_Float16)v[3]};
        *(f16x4*)((_Float16*)Ob + (size_t)n * M + m0) = o;
      } else {
        float4 o = {v[0], v[1], v[2], v[3]};
        *(float4*)((float*)Ob + (size_t)n * M + m0) = o;
      }
    }
  }
}

// ------------------------- fp16 MFMA flash attention ------------------------
// qkvT layout: [b][l][o], o = h*192 + {0..63 q, 64..127 k, 128..191 v}.
// Block = (b,h) x 64 t-tile, 4 waves. Waves SPLIT s: wave w owns s-slice
// w*16.. of each staged 64-s tile, with private online-softmax (m,l).
// S^T[s][t] = mfma32(A=K[s][ch], B=Q^T[ch][t]); C-frag (s=quad*4+i, t=lx)
// feeds PV directly as K=16 B-operand: O[ch][t] += mfma16(A=V^T[ch][s], B=P).
// Cross-wave combine (max/sum over the 4 s-slices) once at the end.
#define LQ 72
#define LV 68
#define LR 68

__global__ __launch_bounds__(256) void attn_mfma(
    const _Float16* __restrict__ qkvT, _Float16* __restrict__ aT) {
  __shared__ __align__(16) char smem[36864];
  _Float16* qs = (_Float16*)smem;        // [t][ch]  64*72*2 = 9216 B
  _Float16* ks = qs + 64 * LQ;           // [s][ch]  9216 B
  _Float16* vs = ks + 64 * LQ;           // [ch][s]  64*68*2 = 8704 B
  float* R0 = (float*)smem;              // [t][ch] f32 64*68*4 = 17408 B
  float* R1 = R0 + 64 * LR;              // second region
  float* mlb = (float*)(smem + 34816);   // [w][{m,l}][64]  2048 B

  const int tid = threadIdx.x;
  const int w = tid >> 6, lane = tid & 63;
  const int lx = lane & 15, quad = lane >> 4;
  const int bh = blockIdx.y, b = bh >> 3, h = bh & 7;
  const int t0 = blockIdx.x * 64;
  const _Float16* qb = qkvT + (size_t)b * 1024 * 1536 + h * 192;

  // ---- stage Q [t][ch] (once) ----
  {
    const int t = tid >> 2, c = (tid & 3) * 16;
    const _Float16* g = qb + (size_t)(t0 + t) * 1536 + c;
    *(f16x8*)&qs[t * LQ + c] = *(const f16x8*)g;
    *(f16x8*)&qs[t * LQ + c + 8] = *(const f16x8*)(g + 8);
  }
  __syncthreads();
  // Q B-frags for all 4 t-subtiles x 2 k-halves (kept in regs all kernel)
  f16x8 qf[4][2];
#pragma unroll
  for (int nt = 0; nt < 4; ++nt)
#pragma unroll
    for (int kh = 0; kh < 2; ++kh)
      qf[nt][kh] = *(const f16x8*)&qs[(nt * 16 + lx) * LQ + kh * 32 + quad * 8];

  float m_r[4] = {-1e30f, -1e30f, -1e30f, -1e30f};
  float l_r[4] = {0.f, 0.f, 0.f, 0.f};
  f32x4 oacc[4][4];  // [mt: ch-subtile][nt: t-subtile]
#pragma unroll
  for (int i = 0; i < 4; ++i)
#pragma unroll
    for (int j = 0; j < 4; ++j) oacc[i][j] = (f32x4){0.f, 0.f, 0.f, 0.f};

  for (int s0 = 0; s0 < 1024; s0 += 64) {
    __syncthreads();  // prior tile's fragment reads complete
    // ---- stage K [s][ch]: direct row copy ----
    {
      const int r = tid >> 2, c = (tid & 3) * 16;
      const _Float16* g = qb + (size_t)(s0 + r) * 1536 + 64 + c;
      *(f16x8*)&ks[r * LQ + c] = *(const f16x8*)g;
      *(f16x8*)&ks[r * LQ + c + 8] = *(const f16x8*)(g + 8);
    }
    // ---- stage V transposed [ch][s], s-pairs packed b32 ----
    {
      const int s2 = (tid >> 3) * 2, c8 = (tid & 7) * 8;
      const _Float16* g = qb + (size_t)(s0 + s2) * 1536 + 128 + c8;
      f16x8 v0 = *(const f16x8*)g;
      f16x8 v1 = *(const f16x8*)(g + 1536);
#pragma unroll
      for (int i = 0; i < 8; ++i) {
        union { _Float16 hh[2]; unsigned u; } p;
        p.hh[0] = v0[i];
        p.hh[1] = v1[i];
        *(unsigned*)&vs[(c8 + i) * LV + s2] = p.u;
      }
    }
    __syncthreads();

    // ---- S^T for this wave's 16-s slice: A=K, B=Q ----
    f16x8 kf0 = *(const f16x8*)&ks[(w * 16 + lx) * LQ + quad * 8];
    f16x8 kf1 = *(const f16x8*)&ks[(w * 16 + lx) * LQ + 32 + quad * 8];
    f32x4 sf[4];
#pragma unroll
    for (int nt = 0; nt < 4; ++nt) {
      f32x4 z = {0.f, 0.f, 0.f, 0.f};
      z = __builtin_amdgcn_mfma_f32_16x16x32_f16(kf0, qf[nt][0], z, 0, 0, 0);
      sf[nt] = __builtin_amdgcn_mfma_f32_16x16x32_f16(kf1, qf[nt][1], z, 0, 0, 0);
#pragma unroll
      for (int i = 0; i < 4; ++i) sf[nt][i] *= 0.125f;
    }

    // ---- online softmax (per t-col, over this wave's 16 s) ----
    // lane holds P[s = w*16 + quad*4 + i][t = nt*16 + lx]
    float mx[4], alpha[4], sum[4];
#pragma unroll
    for (int nt = 0; nt < 4; ++nt) {
      mx[nt] = fmaxf(fmaxf(sf[nt][0], sf[nt][1]), fmaxf(sf[nt][2], sf[nt][3]));
      mx[nt] = fmaxf(mx[nt], __shfl_xor(mx[nt], 16));
      mx[nt] = fmaxf(mx[nt], __shfl_xor(mx[nt], 32));
      float mn = fmaxf(m_r[nt], mx[nt]);
      alpha[nt] = __expf(m_r[nt] - mn);
      m_r[nt] = mn;
    }
    f16x4 pf[4];
#pragma unroll
    for (int nt = 0; nt < 4; ++nt) {
      float p0 = __expf(sf[nt][0] - m_r[nt]);
      float p1 = __expf(sf[nt][1] - m_r[nt]);
      float p2 = __expf(sf[nt][2] - m_r[nt]);
      float p3 = __expf(sf[nt][3] - m_r[nt]);
      sum[nt] = (p0 + p1) + (p2 + p3);
      pf[nt] = (f16x4){(_Float16)p0, (_Float16)p1, (_Float16)p2, (_Float16)p3};
    }
#pragma unroll
    for (int nt = 0; nt < 4; ++nt) {
      sum[nt] += __shfl_xor(sum[nt], 16);
      sum[nt] += __shfl_xor(sum[nt], 32);
      l_r[nt] = l_r[nt] * alpha[nt] + sum[nt];
    }
    // rescale O (skip when no row max changed across the whole wave)
    float am = fminf(fminf(alpha[0], alpha[1]), fminf(alpha[2], alpha[3]));
    if (!__all(am == 1.f)) {
#pragma unroll
      for (int mt = 0; mt < 4; ++mt)
#pragma unroll
        for (int nt = 0; nt < 4; ++nt)
#pragma unroll
          for (int i = 0; i < 4; ++i) oacc[mt][nt][i] *= alpha[nt];
    }

    // ---- PV: O[ch][t] += V^T[ch][s16] * P[s16][t]  (K=16 mfma) ----
    f16x4 vf[4];
#pragma unroll
    for (int mt = 0; mt < 4; ++mt)
      vf[mt] = *(const f16x4*)&vs[(mt * 16 + lx) * LV + w * 16 + quad * 4];
#pragma unroll
    for (int mt = 0; mt < 4; ++mt)
#pragma unroll
      for (int nt = 0; nt < 4; ++nt)
        oacc[mt][nt] = MFMA_K16(vf[mt], pf[nt], oacc[mt][nt]);
  }

  // ---- cross-wave combine: global max/sum over the 4 s-slices ----
  if (quad == 0) {
#pragma unroll
    for (int nt = 0; nt < 4; ++nt) {
      mlb[w * 128 + nt * 16 + lx] = m_r[nt];
      mlb[w * 128 + 64 + nt * 16 + lx] = l_r[nt];
    }
  }
  __syncthreads();
  float cc[4];
#pragma unroll
  for (int nt = 0; nt < 4; ++nt) {
    const int t = nt * 16 + lx;
    float M = -1e30f;
#pragma unroll
    for (int w2 = 0; w2 < 4; ++w2) M = fmaxf(M, mlb[w2 * 128 + t]);
    float L = 0.f;
#pragma unroll
    for (int w2 = 0; w2 < 4; ++w2)
      L += mlb[w2 * 128 + 64 + t] * __expf(mlb[w2 * 128 + t] - M);
    cc[nt] = __expf(m_r[nt] - M) / L;
  }
#pragma unroll
  for (int mt = 0; mt < 4; ++mt)
#pragma unroll
    for (int nt = 0; nt < 4; ++nt)
#pragma unroll
      for (int i = 0; i < 4; ++i) oacc[mt][nt][i] *= cc[nt];

  // R regions hold O^T as [t][ch] f32 (frag regs i = contiguous ch -> b128)
  if (w < 2) {
    float* R = w ? R1 : R0;
#pragma unroll
    for (int mt = 0; mt < 4; ++mt)
#pragma unroll
      for (int nt = 0; nt < 4; ++nt)
        *(f32x4*)&R[(nt * 16 + lx) * LR + mt * 16 + quad * 4] = oacc[mt][nt];
  }
  __syncthreads();
  if (w >= 2) {
    float* R = (w == 3) ? R1 : R0;
#pragma unroll
    for (int mt = 0; mt < 4; ++mt)
#pragma unroll
      for (int nt = 0; nt < 4; ++nt) {
        f32x4 r = *(f32x4*)&R[(nt * 16 + lx) * LR + mt * 16 + quad * 4];
        r += oacc[mt][nt];
        *(f32x4*)&R[(nt * 16 + lx) * LR + mt * 16 + quad * 4] = r;
      }
  }
  __syncthreads();

  // ---- store aT[b][t][h*64+ch] = R0 + R1 ----
  {
    const int t = tid >> 2, cb = (tid & 3) * 16;
    f16x8 o0, o1;
#pragma unroll
    for (int j = 0; j < 8; ++j) {
      o0[j] = (_Float16)(R0[t * LR + cb + j] + R1[t * LR + cb + j]);
      o1[j] = (_Float16)(R0[t * LR + cb + 8 + j] + R1[t * LR + cb + 8 + j]);
    }
    _Float16* ob = aT + ((size_t)b * 1024 + t0 + t) * 512 + h * 64 + cb;
    *(f16x8*)ob = o0;
    *(f16x8*)(ob + 8) = o1;
  }
}

// ---------------------------------------------------------------------------
extern "C" void kernel_launch(void* const* d_in, const int* in_sizes, int n_in,
                              void* d_out, int out_size, void* d_ws,
                              size_t ws_size, hipStream_t stream) {
  const float* x = (const float*)d_in[0];
  const float* norm_w = (const float*)d_in[1];
  const float* norm_b = (const float*)d_in[2];
  const float* w_qkv = (const float*)d_in[3];
  const float* b_qkv = (const float*)d_in[4];
  const float* w_proj = (const float*)d_in[5];
  const float* b_proj = (const float*)d_in[6];
  float* out = (float*)d_out;

  _Float16* hT = (_Float16*)d_ws;
  _Float16* qkvT = hT + (size_t)16 * 1024 * 512;
  _Float16* wq = qkvT + (size_t)16 * 1024 * 1536;
  _Float16* wp = wq + (size_t)1536 * 512;
  _Float16* aT = hT;

  f32_to_f16<<<768, 256, 0, stream>>>(w_qkv, wq, 196608);
  f32_to_f16<<<256, 256, 0, stream>>>(w_proj, wp, 65536);
  gn_kernel<<<512, 256, 0, stream>>>(x, norm_w, norm_b, hT);
  gemm_tn<_Float16, true><<<dim3(8, 12, 16), 256, 0, stream>>>(
      wq, hT, b_qkv, qkvT, 1536, 1024, 512, 0L, 524288L);
  attn_mfma<<<dim3(16, 128), 256, 0, stream>>>(qkvT, aT);
  gemm_tn<float, false><<<dim3(4, 8, 16), 256, 0, stream>>>(
      aT, wp, b_proj, out, 1024, 512, 512, 524288L, 0L);
}

// Round 6
// 247.278 us; speedup vs baseline: 4.2049x; 1.2069x over previous
//
#include <hip/hip_runtime.h>
#include <math.h>

// ---------------------------------------------------------------------------
// AttentionBlock: GroupNorm(32) -> QKV proj -> MHA(8 heads) -> out proj
// B=16, C=512, L=1024, group=16ch, head ch=64.
// Round 6: attn = P-in-registers flash (R5 trick) but waves split T not S:
//   - O per wave = 64ch x 16t -> 16 AGPRs (R5: 64) -> occupancy cliff fixed
//   - Q B-frags loaded DIRECTLY from global (no Q LDS, no extra barrier)
//   - no cross-wave combine; m/l are lane-scalars
// ---------------------------------------------------------------------------

typedef _Float16 f16x8 __attribute__((ext_vector_type(8)));
typedef _Float16 f16x4 __attribute__((ext_vector_type(4)));
typedef float f32x4 __attribute__((ext_vector_type(4)));

// NOTE: legacy K=16 fp16 MFMA builtin has NO underscore before f16.
#define MFMA_K16(A, B, C) __builtin_amdgcn_mfma_f32_16x16x16f16(A, B, C, 0, 0, 0)

// ------------------------- weight fp32 -> fp16 ------------------------------
__global__ __launch_bounds__(256) void f32_to_f16(
    const float* __restrict__ src, _Float16* __restrict__ dst, int n4) {
  int i = blockIdx.x * 256 + threadIdx.x;
  if (i < n4) {
    float4 v = ((const float4*)src)[i];
    f16x4 o = {(_Float16)v.x, (_Float16)v.y, (_Float16)v.z, (_Float16)v.w};
    *(f16x4*)&dst[(size_t)i * 4] = o;
  }
}

// ------------------------- GroupNorm (writes hT [b][l][c] fp16) -------------
__global__ __launch_bounds__(256) void gn_kernel(
    const float* __restrict__ x, const float* __restrict__ gw,
    const float* __restrict__ gb, _Float16* __restrict__ hT) {
  const int b = blockIdx.x >> 5;
  const int g = blockIdx.x & 31;
  const size_t base = ((size_t)(b * 512 + g * 16)) * 1024;
  const float4* xp = (const float4*)(x + base);
  const int tid = threadIdx.x;

  float4 vals[16];
  float s = 0.f, sq = 0.f;
#pragma unroll
  for (int r = 0; r < 16; ++r) {
    float4 v = xp[tid + 256 * r];
    vals[r] = v;
    s += v.x + v.y + v.z + v.w;
    sq += v.x * v.x + v.y * v.y + v.z * v.z + v.w * v.w;
  }
  __shared__ float rs[256];
  __shared__ float rq[256];
  rs[tid] = s;
  rq[tid] = sq;
  __syncthreads();
  for (int off = 128; off > 0; off >>= 1) {
    if (tid < off) {
      rs[tid] += rs[tid + off];
      rq[tid] += rq[tid + off];
    }
    __syncthreads();
  }
  const float mean = rs[0] * (1.f / 16384.f);
  const float var = rq[0] * (1.f / 16384.f) - mean * mean;
  const float rinv = rsqrtf(var + 1e-5f);
#pragma unroll
  for (int r = 0; r < 16; ++r) {
    const int c = g * 16 + r;
    const float wc = gw[c] * rinv;
    const float bc = gb[c] - mean * wc;
    vals[r].x = vals[r].x * wc + bc;
    vals[r].y = vals[r].y * wc + bc;
    vals[r].z = vals[r].z * wc + bc;
    vals[r].w = vals[r].w * wc + bc;
  }
  _Float16* hb = hT + ((size_t)b * 1024 + tid * 4) * 512 + g * 16;
#pragma unroll
  for (int li = 0; li < 4; ++li) {
    f16x8 o0, o1;
#pragma unroll
    for (int r = 0; r < 8; ++r) {
      float v0 = li == 0 ? vals[r].x : li == 1 ? vals[r].y
                 : li == 2 ? vals[r].z : vals[r].w;
      float v1 = li == 0 ? vals[8 + r].x : li == 1 ? vals[8 + r].y
                 : li == 2 ? vals[8 + r].z : vals[8 + r].w;
      o0[r] = (_Float16)v0;
      o1[r] = (_Float16)v1;
    }
    *(f16x8*)(hb + (size_t)li * 512) = o0;
    *(f16x8*)(hb + (size_t)li * 512 + 8) = o1;
  }
}

// ------------------------- fp16 MFMA GEMM (unchanged R3) --------------------
template <typename OutT, bool BIAS_ON_M>
__global__ __launch_bounds__(256) void gemm_tn(
    const _Float16* __restrict__ A, const _Float16* __restrict__ B,
    const float* __restrict__ bias, OutT* __restrict__ Out,
    int M, int N, int K, long sA, long sB) {
  __shared__ __align__(16) _Float16 As[128 * 32];
  __shared__ __align__(16) _Float16 Bs[128 * 32];
  const int tid = threadIdx.x;
  const int w = tid >> 6, lane = tid & 63;
  const int lx = lane & 15, quad = lane >> 4;
  const int wm = w >> 1, wn = w & 1;
  const int bn = blockIdx.x * 128, bm = blockIdx.y * 128;
  const int z = blockIdx.z;
  const int srow = tid >> 1;
  const int shalf = (tid & 1) * 16;
  const _Float16* Ag = A + (size_t)z * sA + (size_t)(bm + srow) * K + shalf;
  const _Float16* Bg = B + (size_t)z * sB + (size_t)(bn + srow) * K + shalf;
  _Float16* Asw = &As[srow * 32 + shalf];
  _Float16* Bsw = &Bs[srow * 32 + shalf];

  f32x4 acc[4][4];
#pragma unroll
  for (int i = 0; i < 4; ++i)
#pragma unroll
    for (int j = 0; j < 4; ++j) acc[i][j] = (f32x4){0.f, 0.f, 0.f, 0.f};

  for (int k0 = 0; k0 < K; k0 += 32) {
    f16x8 a0 = *(const f16x8*)(Ag + k0);
    f16x8 a1 = *(const f16x8*)(Ag + k0 + 8);
    f16x8 b0 = *(const f16x8*)(Bg + k0);
    f16x8 b1 = *(const f16x8*)(Bg + k0 + 8);
    __syncthreads();
    *(f16x8*)Asw = a0;
    *(f16x8*)(Asw + 8) = a1;
    *(f16x8*)Bsw = b0;
    *(f16x8*)(Bsw + 8) = b1;
    __syncthreads();
    f16x8 af[4], bf[4];
#pragma unroll
    for (int mt = 0; mt < 4; ++mt)
      af[mt] = *(const f16x8*)&As[(wm * 64 + mt * 16 + lx) * 32 + quad * 8];
#pragma unroll
    for (int nt = 0; nt < 4; ++nt)
      bf[nt] = *(const f16x8*)&Bs[(wn * 64 + nt * 16 + lx) * 32 + quad * 8];
#pragma unroll
    for (int mt = 0; mt < 4; ++mt)
#pragma unroll
      for (int nt = 0; nt < 4; ++nt)
        acc[mt][nt] = __builtin_amdgcn_mfma_f32_16x16x32_f16(
            af[mt], bf[nt], acc[mt][nt], 0, 0, 0);
  }

  OutT* Ob = Out + (size_t)z * M * N;
#pragma unroll
  for (int mt = 0; mt < 4; ++mt) {
    const int m0 = bm + wm * 64 + mt * 16 + quad * 4;
    float bm4[4];
#pragma unroll
    for (int i = 0; i < 4; ++i) bm4[i] = BIAS_ON_M ? bias[m0 + i] : 0.f;
#pragma unroll
    for (int nt = 0; nt < 4; ++nt) {
      const int n = bn + wn * 64 + nt * 16 + lx;
      const float bn1 = BIAS_ON_M ? 0.f : bias[n];
      float v[4];
#pragma unroll
      for (int i = 0; i < 4; ++i)
        v[i] = acc[mt][nt][i] + (BIAS_ON_M ? bm4[i] : bn1);
      if constexpr (sizeof(OutT) == 2) {
        f16x4 o = {(_Float16)v[0], (_Float16)v[1], (_Float16)v[2],
                   (_Float16)v[3]};
        *(f16x4*)((_Float16*)Ob + (size_t)n * M + m0) = o;
      } else {
        float4 o = {v[0], v[1], v[2], v[3]};
        *(float4*)((float*)Ob + (size_t)n * M + m0) = o;
      }
    }
  }
}

// ------------------------- fp16 MFMA flash attention ------------------------
// qkvT layout: [b][l][o], o = h*192 + {0..63 q, 64..127 k, 128..191 v}.
// Block = (b,h) x 64 t-tile, 4 waves. Wave w owns t-cols w*16..w*16+15 for the
// FULL s range. Per s-tile (64): S^T[s][t] = mfma32(A=K[s][ch], B=Q^T[ch][t])
// over 4 s-subtiles; each C-frag (s=quad*4+i, t=lx) is directly the K=16
// B-operand for PV: O[ch][t] += mfma16(A=V^T[ch][s16], B=P[s16][t]).
// m/l are lane-scalars (col t = w*16+lx); no cross-wave combine.
#define LQ 72
#define LV 68

__global__ __launch_bounds__(256) void attn_mfma(
    const _Float16* __restrict__ qkvT, _Float16* __restrict__ aT) {
  __shared__ __align__(16) _Float16 ks[64 * LQ];  // [s][ch]  9216 B
  __shared__ __align__(16) _Float16 vs[64 * LV];  // [ch][s]  8704 B

  const int tid = threadIdx.x;
  const int w = tid >> 6, lane = tid & 63;
  const int lx = lane & 15, quad = lane >> 4;
  const int bh = blockIdx.y, b = bh >> 3, h = bh & 7;
  const int t0 = blockIdx.x * 64;
  const _Float16* qb = qkvT + (size_t)b * 1024 * 1536 + h * 192;

  // ---- Q B-frags straight from global (once): B[k=ch][n=t], t=w*16+lx ----
  const _Float16* qrow = qb + (size_t)(t0 + w * 16 + lx) * 1536;
  const f16x8 qf0 = *(const f16x8*)(qrow + quad * 8);
  const f16x8 qf1 = *(const f16x8*)(qrow + 32 + quad * 8);

  float m_r = -1e30f, l_r = 0.f;
  f32x4 oacc[4];  // D[m=ch: mt*16+quad*4+i][n=t: w*16+lx]
#pragma unroll
  for (int mt = 0; mt < 4; ++mt) oacc[mt] = (f32x4){0.f, 0.f, 0.f, 0.f};

  for (int s0 = 0; s0 < 1024; s0 += 64) {
    __syncthreads();  // prior tile's fragment reads complete
    // ---- stage K [s][ch]: direct row copy ----
    {
      const int r = tid >> 2, c = (tid & 3) * 16;
      const _Float16* g = qb + (size_t)(s0 + r) * 1536 + 64 + c;
      *(f16x8*)&ks[r * LQ + c] = *(const f16x8*)g;
      *(f16x8*)&ks[r * LQ + c + 8] = *(const f16x8*)(g + 8);
    }
    // ---- stage V transposed [ch][s], s-pairs packed b32 ----
    {
      const int s2 = (tid >> 3) * 2, c8 = (tid & 7) * 8;
      const _Float16* g = qb + (size_t)(s0 + s2) * 1536 + 128 + c8;
      f16x8 v0 = *(const f16x8*)g;
      f16x8 v1 = *(const f16x8*)(g + 1536);
#pragma unroll
      for (int i = 0; i < 8; ++i) {
        union { _Float16 hh[2]; unsigned u; } p;
        p.hh[0] = v0[i];
        p.hh[1] = v1[i];
        *(unsigned*)&vs[(c8 + i) * LV + s2] = p.u;
      }
    }
    __syncthreads();

    // ---- S^T[s][t] for this wave's 16 t-cols, all 64 s (4 subtiles) ----
    f32x4 sf[4];
#pragma unroll
    for (int sb = 0; sb < 4; ++sb) {
      f16x8 k0 = *(const f16x8*)&ks[(sb * 16 + lx) * LQ + quad * 8];
      f16x8 k1 = *(const f16x8*)&ks[(sb * 16 + lx) * LQ + 32 + quad * 8];
      f32x4 z = {0.f, 0.f, 0.f, 0.f};
      z = __builtin_amdgcn_mfma_f32_16x16x32_f16(k0, qf0, z, 0, 0, 0);
      sf[sb] = __builtin_amdgcn_mfma_f32_16x16x32_f16(k1, qf1, z, 0, 0, 0);
#pragma unroll
      for (int i = 0; i < 4; ++i) sf[sb][i] *= 0.125f;
    }

    // ---- online softmax for col t=w*16+lx (lane-scalar m/l) ----
    // lane holds S[s = sb*16 + quad*4 + i][t]; col spans 4 quad-lanes.
    float mx = sf[0][0];
#pragma unroll
    for (int sb = 0; sb < 4; ++sb)
#pragma unroll
      for (int i = 0; i < 4; ++i) mx = fmaxf(mx, sf[sb][i]);
    mx = fmaxf(mx, __shfl_xor(mx, 16));
    mx = fmaxf(mx, __shfl_xor(mx, 32));
    const float mn = fmaxf(m_r, mx);
    const float alpha = __expf(m_r - mn);
    m_r = mn;
    float sum = 0.f;
    f16x4 pf[4];
#pragma unroll
    for (int sb = 0; sb < 4; ++sb) {
      float p0 = __expf(sf[sb][0] - mn);
      float p1 = __expf(sf[sb][1] - mn);
      float p2 = __expf(sf[sb][2] - mn);
      float p3 = __expf(sf[sb][3] - mn);
      sum += (p0 + p1) + (p2 + p3);
      pf[sb] = (f16x4){(_Float16)p0, (_Float16)p1, (_Float16)p2, (_Float16)p3};
    }
    sum += __shfl_xor(sum, 16);
    sum += __shfl_xor(sum, 32);
    l_r = l_r * alpha + sum;
    if (!__all(alpha == 1.f)) {
#pragma unroll
      for (int mt = 0; mt < 4; ++mt)
#pragma unroll
        for (int i = 0; i < 4; ++i) oacc[mt][i] *= alpha;
    }

    // ---- PV: O[ch][t] += V^T[ch][s16] * P[s16][t]  (K=16 mfma) ----
#pragma unroll
    for (int kb = 0; kb < 4; ++kb)
#pragma unroll
      for (int mt = 0; mt < 4; ++mt) {
        f16x4 vf = *(const f16x4*)&vs[(mt * 16 + lx) * LV + kb * 16 + quad * 4];
        oacc[mt] = MFMA_K16(vf, pf[kb], oacc[mt]);
      }
  }

  // ---- epilogue: aT[b][t][h*64+ch] = O/l (all lane-local) ----
  const float linv = 1.f / l_r;
  _Float16* ob = aT + ((size_t)b * 1024 + t0 + w * 16 + lx) * 512 + h * 64;
#pragma unroll
  for (int mt = 0; mt < 4; ++mt) {
    f16x4 o = {(_Float16)(oacc[mt][0] * linv), (_Float16)(oacc[mt][1] * linv),
               (_Float16)(oacc[mt][2] * linv), (_Float16)(oacc[mt][3] * linv)};
    *(f16x4*)&ob[mt * 16 + quad * 4] = o;
  }
}

// ---------------------------------------------------------------------------
extern "C" void kernel_launch(void* const* d_in, const int* in_sizes, int n_in,
                              void* d_out, int out_size, void* d_ws,
                              size_t ws_size, hipStream_t stream) {
  const float* x = (const float*)d_in[0];
  const float* norm_w = (const float*)d_in[1];
  const float* norm_b = (const float*)d_in[2];
  const float* w_qkv = (const float*)d_in[3];
  const float* b_qkv = (const float*)d_in[4];
  const float* w_proj = (const float*)d_in[5];
  const float* b_proj = (const float*)d_in[6];
  float* out = (float*)d_out;

  _Float16* hT = (_Float16*)d_ws;
  _Float16* qkvT = hT + (size_t)16 * 1024 * 512;
  _Float16* wq = qkvT + (size_t)16 * 1024 * 1536;
  _Float16* wp = wq + (size_t)1536 * 512;
  _Float16* aT = hT;

  f32_to_f16<<<768, 256, 0, stream>>>(w_qkv, wq, 196608);
  f32_to_f16<<<256, 256, 0, stream>>>(w_proj, wp, 65536);
  gn_kernel<<<512, 256, 0, stream>>>(x, norm_w, norm_b, hT);
  gemm_tn<_Float16, true><<<dim3(8, 12, 16), 256, 0, stream>>>(
      wq, hT, b_qkv, qkvT, 1536, 1024, 512, 0L, 524288L);
  attn_mfma<<<dim3(16, 128), 256, 0, stream>>>(qkvT, aT);
  gemm_tn<float, false><<<dim3(4, 8, 16), 256, 0, stream>>>(
      aT, wp, b_proj, out, 1024, 512, 512, 524288L, 0L);
}

// Round 7
// 244.508 us; speedup vs baseline: 4.2525x; 1.0113x over previous
//
#include <hip/hip_runtime.h>
#include <math.h>

// ---------------------------------------------------------------------------
// AttentionBlock: GroupNorm(32) -> QKV proj -> MHA(8 heads) -> out proj
// B=16, C=512, L=1024, group=16ch, head ch=64.
// Round 7: GEMMs use async global->LDS staging (global_load_lds width=16,
// m97 structure). Attn: 1/8 scale folded into Q frags (exact pow2 in fp16).
// ---------------------------------------------------------------------------

typedef _Float16 f16x8 __attribute__((ext_vector_type(8)));
typedef _Float16 f16x4 __attribute__((ext_vector_type(4)));
typedef float f32x4 __attribute__((ext_vector_type(4)));

// NOTE: legacy K=16 fp16 MFMA builtin has NO underscore before f16.
#define MFMA_K16(A, B, C) __builtin_amdgcn_mfma_f32_16x16x16f16(A, B, C, 0, 0, 0)

// async 16B/lane global->LDS copy. LDS dest is WAVE-UNIFORM base; HW places
// lane i at base + i*16. Global src is per-lane.
__device__ __forceinline__ void async_cp16(const void* g, void* l) {
  __builtin_amdgcn_global_load_lds(
      (const __attribute__((address_space(1))) void*)g,
      (__attribute__((address_space(3))) void*)l, 16, 0, 0);
}

// ------------------------- weight fp32 -> fp16 ------------------------------
__global__ __launch_bounds__(256) void f32_to_f16(
    const float* __restrict__ src, _Float16* __restrict__ dst, int n4) {
  int i = blockIdx.x * 256 + threadIdx.x;
  if (i < n4) {
    float4 v = ((const float4*)src)[i];
    f16x4 o = {(_Float16)v.x, (_Float16)v.y, (_Float16)v.z, (_Float16)v.w};
    *(f16x4*)&dst[(size_t)i * 4] = o;
  }
}

// ------------------------- GroupNorm (writes hT [b][l][c] fp16) -------------
__global__ __launch_bounds__(256) void gn_kernel(
    const float* __restrict__ x, const float* __restrict__ gw,
    const float* __restrict__ gb, _Float16* __restrict__ hT) {
  const int b = blockIdx.x >> 5;
  const int g = blockIdx.x & 31;
  const size_t base = ((size_t)(b * 512 + g * 16)) * 1024;
  const float4* xp = (const float4*)(x + base);
  const int tid = threadIdx.x;

  float4 vals[16];
  float s = 0.f, sq = 0.f;
#pragma unroll
  for (int r = 0; r < 16; ++r) {
    float4 v = xp[tid + 256 * r];
    vals[r] = v;
    s += v.x + v.y + v.z + v.w;
    sq += v.x * v.x + v.y * v.y + v.z * v.z + v.w * v.w;
  }
  __shared__ float rs[256];
  __shared__ float rq[256];
  rs[tid] = s;
  rq[tid] = sq;
  __syncthreads();
  for (int off = 128; off > 0; off >>= 1) {
    if (tid < off) {
      rs[tid] += rs[tid + off];
      rq[tid] += rq[tid + off];
    }
    __syncthreads();
  }
  const float mean = rs[0] * (1.f / 16384.f);
  const float var = rq[0] * (1.f / 16384.f) - mean * mean;
  const float rinv = rsqrtf(var + 1e-5f);
#pragma unroll
  for (int r = 0; r < 16; ++r) {
    const int c = g * 16 + r;
    const float wc = gw[c] * rinv;
    const float bc = gb[c] - mean * wc;
    vals[r].x = vals[r].x * wc + bc;
    vals[r].y = vals[r].y * wc + bc;
    vals[r].z = vals[r].z * wc + bc;
    vals[r].w = vals[r].w * wc + bc;
  }
  _Float16* hb = hT + ((size_t)b * 1024 + tid * 4) * 512 + g * 16;
#pragma unroll
  for (int li = 0; li < 4; ++li) {
    f16x8 o0, o1;
#pragma unroll
    for (int r = 0; r < 8; ++r) {
      float v0 = li == 0 ? vals[r].x : li == 1 ? vals[r].y
                 : li == 2 ? vals[r].z : vals[r].w;
      float v1 = li == 0 ? vals[8 + r].x : li == 1 ? vals[8 + r].y
                 : li == 2 ? vals[8 + r].z : vals[8 + r].w;
      o0[r] = (_Float16)v0;
      o1[r] = (_Float16)v1;
    }
    *(f16x8*)(hb + (size_t)li * 512) = o0;
    *(f16x8*)(hb + (size_t)li * 512 + 8) = o1;
  }
}

// ------------------------- fp16 MFMA GEMM, async staging --------------------
// C[m][n] = sum_k A[m][k]*B[n][k] (+bias), stored TRANSPOSED: Out[n][m].
// A: [M][K] fp16 k-contig. B: [N][K] fp16 k-contig. 128x128 tile, BK=32.
// Staging: global_load_lds 16B/lane; wave w owns As rows [w*16,w*16+16) and
// [64+w*16, ...), same for Bs. As rows are 64B, chunk = 16 rows = 1KB = one
// wave-issue (lane i -> row i/4, 16B-slot i%4) — matches HW lane placement.
template <typename OutT, bool BIAS_ON_M>
__global__ __launch_bounds__(256) void gemm_tn(
    const _Float16* __restrict__ A, const _Float16* __restrict__ B,
    const float* __restrict__ bias, OutT* __restrict__ Out,
    int M, int N, int K, long sA, long sB) {
  __shared__ __align__(16) _Float16 As[128 * 32];  // 8KB, 64B rows, no pad
  __shared__ __align__(16) _Float16 Bs[128 * 32];  // 8KB
  const int tid = threadIdx.x;
  const int w = tid >> 6, lane = tid & 63;
  const int lx = lane & 15, quad = lane >> 4;
  const int wm = w >> 1, wn = w & 1;
  const int bn = blockIdx.x * 128, bm = blockIdx.y * 128;
  const int z = blockIdx.z;

  // staging addresses: chunk0 rows [w*16, w*16+16), chunk1 rows +64
  const int cr = w * 16;
  const int lrow = lane >> 2;        // 0..15 within chunk
  const int lk = (lane & 3) * 8;     // f16 offset: 0,8,16,24 (16B slots)
  const _Float16* Ag = A + (size_t)z * sA + (size_t)(bm + cr + lrow) * K + lk;
  const _Float16* Bg = B + (size_t)z * sB + (size_t)(bn + cr + lrow) * K + lk;
  _Float16* As0 = &As[cr * 32];          // wave-uniform LDS chunk bases
  _Float16* As1 = &As[(cr + 64) * 32];
  _Float16* Bs0 = &Bs[cr * 32];
  _Float16* Bs1 = &Bs[(cr + 64) * 32];

  f32x4 acc[4][4];
#pragma unroll
  for (int i = 0; i < 4; ++i)
#pragma unroll
    for (int j = 0; j < 4; ++j) acc[i][j] = (f32x4){0.f, 0.f, 0.f, 0.f};

  for (int k0 = 0; k0 < K; k0 += 32) {
    __syncthreads();  // prior iteration's frag reads complete
    async_cp16(Ag + k0, As0);
    async_cp16(Ag + (size_t)64 * K + k0, As1);
    async_cp16(Bg + k0, Bs0);
    async_cp16(Bg + (size_t)64 * K + k0, Bs1);
    __syncthreads();  // drains vmcnt -> staged data visible
    f16x8 af[4], bf[4];
#pragma unroll
    for (int mt = 0; mt < 4; ++mt)
      af[mt] = *(const f16x8*)&As[(wm * 64 + mt * 16 + lx) * 32 + quad * 8];
#pragma unroll
    for (int nt = 0; nt < 4; ++nt)
      bf[nt] = *(const f16x8*)&Bs[(wn * 64 + nt * 16 + lx) * 32 + quad * 8];
#pragma unroll
    for (int mt = 0; mt < 4; ++mt)
#pragma unroll
      for (int nt = 0; nt < 4; ++nt)
        acc[mt][nt] = __builtin_amdgcn_mfma_f32_16x16x32_f16(
            af[mt], bf[nt], acc[mt][nt], 0, 0, 0);
  }

  OutT* Ob = Out + (size_t)z * M * N;
#pragma unroll
  for (int mt = 0; mt < 4; ++mt) {
    const int m0 = bm + wm * 64 + mt * 16 + quad * 4;
    float bm4[4];
#pragma unroll
    for (int i = 0; i < 4; ++i) bm4[i] = BIAS_ON_M ? bias[m0 + i] : 0.f;
#pragma unroll
    for (int nt = 0; nt < 4; ++nt) {
      const int n = bn + wn * 64 + nt * 16 + lx;
      const float bn1 = BIAS_ON_M ? 0.f : bias[n];
      float v[4];
#pragma unroll
      for (int i = 0; i < 4; ++i)
        v[i] = acc[mt][nt][i] + (BIAS_ON_M ? bm4[i] : bn1);
      if constexpr (sizeof(OutT) == 2) {
        f16x4 o = {(_Float16)v[0], (_Float16)v[1], (_Float16)v[2],
                   (_Float16)v[3]};
        *(f16x4*)((_Float16*)Ob + (size_t)n * M + m0) = o;
      } else {
        float4 o = {v[0], v[1], v[2], v[3]};
        *(float4*)((float*)Ob + (size_t)n * M + m0) = o;
      }
    }
  }
}

// ------------------------- fp16 MFMA flash attention ------------------------
// qkvT layout: [b][l][o], o = h*192 + {0..63 q, 64..127 k, 128..191 v}.
// Block = (b,h) x 64 t-tile, 4 waves; wave w owns t-cols w*16..+15, full s.
// S^T[s][t] = mfma32(A=K[s][ch], B=Q^T[ch][t]); C-frag directly feeds PV as
// the K=16 B-operand. Scale 1/8 pre-folded into Q frags (exact pow2).
#define LQ 72
#define LV 68

__global__ __launch_bounds__(256) void attn_mfma(
    const _Float16* __restrict__ qkvT, _Float16* __restrict__ aT) {
  __shared__ __align__(16) _Float16 ks[64 * LQ];  // [s][ch]  9216 B
  __shared__ __align__(16) _Float16 vs[64 * LV];  // [ch][s]  8704 B

  const int tid = threadIdx.x;
  const int w = tid >> 6, lane = tid & 63;
  const int lx = lane & 15, quad = lane >> 4;
  const int bh = blockIdx.y, b = bh >> 3, h = bh & 7;
  const int t0 = blockIdx.x * 64;
  const _Float16* qb = qkvT + (size_t)b * 1024 * 1536 + h * 192;

  // ---- Q B-frags straight from global (once), scale 1/8 folded in ----
  const _Float16* qrow = qb + (size_t)(t0 + w * 16 + lx) * 1536;
  f16x8 qf0 = *(const f16x8*)(qrow + quad * 8);
  f16x8 qf1 = *(const f16x8*)(qrow + 32 + quad * 8);
#pragma unroll
  for (int j = 0; j < 8; ++j) {
    qf0[j] = qf0[j] * (_Float16)0.125f;
    qf1[j] = qf1[j] * (_Float16)0.125f;
  }

  float m_r = -1e30f, l_r = 0.f;
  f32x4 oacc[4];  // D[m=ch: mt*16+quad*4+i][n=t: w*16+lx]
#pragma unroll
  for (int mt = 0; mt < 4; ++mt) oacc[mt] = (f32x4){0.f, 0.f, 0.f, 0.f};

  for (int s0 = 0; s0 < 1024; s0 += 64) {
    __syncthreads();  // prior tile's fragment reads complete
    // ---- stage K [s][ch]: direct row copy ----
    {
      const int r = tid >> 2, c = (tid & 3) * 16;
      const _Float16* g = qb + (size_t)(s0 + r) * 1536 + 64 + c;
      *(f16x8*)&ks[r * LQ + c] = *(const f16x8*)g;
      *(f16x8*)&ks[r * LQ + c + 8] = *(const f16x8*)(g + 8);
    }
    // ---- stage V transposed [ch][s], s-pairs packed b32 ----
    {
      const int s2 = (tid >> 3) * 2, c8 = (tid & 7) * 8;
      const _Float16* g = qb + (size_t)(s0 + s2) * 1536 + 128 + c8;
      f16x8 v0 = *(const f16x8*)g;
      f16x8 v1 = *(const f16x8*)(g + 1536);
#pragma unroll
      for (int i = 0; i < 8; ++i) {
        union { _Float16 hh[2]; unsigned u; } p;
        p.hh[0] = v0[i];
        p.hh[1] = v1[i];
        *(unsigned*)&vs[(c8 + i) * LV + s2] = p.u;
      }
    }
    __syncthreads();

    // ---- S^T[s][t] for this wave's 16 t-cols, all 64 s (4 subtiles) ----
    f32x4 sf[4];
#pragma unroll
    for (int sb = 0; sb < 4; ++sb) {
      f16x8 k0 = *(const f16x8*)&ks[(sb * 16 + lx) * LQ + quad * 8];
      f16x8 k1 = *(const f16x8*)&ks[(sb * 16 + lx) * LQ + 32 + quad * 8];
      f32x4 z = {0.f, 0.f, 0.f, 0.f};
      z = __builtin_amdgcn_mfma_f32_16x16x32_f16(k0, qf0, z, 0, 0, 0);
      sf[sb] = __builtin_amdgcn_mfma_f32_16x16x32_f16(k1, qf1, z, 0, 0, 0);
    }

    // ---- online softmax for col t=w*16+lx (lane-scalar m/l) ----
    float mx = sf[0][0];
#pragma unroll
    for (int sb = 0; sb < 4; ++sb)
#pragma unroll
      for (int i = 0; i < 4; ++i) mx = fmaxf(mx, sf[sb][i]);
    mx = fmaxf(mx, __shfl_xor(mx, 16));
    mx = fmaxf(mx, __shfl_xor(mx, 32));
    const float mn = fmaxf(m_r, mx);
    const float alpha = __expf(m_r - mn);
    m_r = mn;
    float sum = 0.f;
    f16x4 pf[4];
#pragma unroll
    for (int sb = 0; sb < 4; ++sb) {
      float p0 = __expf(sf[sb][0] - mn);
      float p1 = __expf(sf[sb][1] - mn);
      float p2 = __expf(sf[sb][2] - mn);
      float p3 = __expf(sf[sb][3] - mn);
      sum += (p0 + p1) + (p2 + p3);
      pf[sb] = (f16x4){(_Float16)p0, (_Float16)p1, (_Float16)p2, (_Float16)p3};
    }
    sum += __shfl_xor(sum, 16);
    sum += __shfl_xor(sum, 32);
    l_r = l_r * alpha + sum;
    if (!__all(alpha == 1.f)) {
#pragma unroll
      for (int mt = 0; mt < 4; ++mt)
#pragma unroll
        for (int i = 0; i < 4; ++i) oacc[mt][i] *= alpha;
    }

    // ---- PV: O[ch][t] += V^T[ch][s16] * P[s16][t]  (K=16 mfma) ----
#pragma unroll
    for (int kb = 0; kb < 4; ++kb)
#pragma unroll
      for (int mt = 0; mt < 4; ++mt) {
        f16x4 vf = *(const f16x4*)&vs[(mt * 16 + lx) * LV + kb * 16 + quad * 4];
        oacc[mt] = MFMA_K16(vf, pf[kb], oacc[mt]);
      }
  }

  // ---- epilogue: aT[b][t][h*64+ch] = O/l (all lane-local) ----
  const float linv = 1.f / l_r;
  _Float16* ob = aT + ((size_t)b * 1024 + t0 + w * 16 + lx) * 512 + h * 64;
#pragma unroll
  for (int mt = 0; mt < 4; ++mt) {
    f16x4 o = {(_Float16)(oacc[mt][0] * linv), (_Float16)(oacc[mt][1] * linv),
               (_Float16)(oacc[mt][2] * linv), (_Float16)(oacc[mt][3] * linv)};
    *(f16x4*)&ob[mt * 16 + quad * 4] = o;
  }
}

// ---------------------------------------------------------------------------
extern "C" void kernel_launch(void* const* d_in, const int* in_sizes, int n_in,
                              void* d_out, int out_size, void* d_ws,
                              size_t ws_size, hipStream_t stream) {
  const float* x = (const float*)d_in[0];
  const float* norm_w = (const float*)d_in[1];
  const float* norm_b = (const float*)d_in[2];
  const float* w_qkv = (const float*)d_in[3];
  const float* b_qkv = (const float*)d_in[4];
  const float* w_proj = (const float*)d_in[5];
  const float* b_proj = (const float*)d_in[6];
  float* out = (float*)d_out;

  _Float16* hT = (_Float16*)d_ws;
  _Float16* qkvT = hT + (size_t)16 * 1024 * 512;
  _Float16* wq = qkvT + (size_t)16 * 1024 * 1536;
  _Float16* wp = wq + (size_t)1536 * 512;
  _Float16* aT = hT;

  f32_to_f16<<<768, 256, 0, stream>>>(w_qkv, wq, 196608);
  f32_to_f16<<<256, 256, 0, stream>>>(w_proj, wp, 65536);
  gn_kernel<<<512, 256, 0, stream>>>(x, norm_w, norm_b, hT);
  gemm_tn<_Float16, true><<<dim3(8, 12, 16), 256, 0, stream>>>(
      wq, hT, b_qkv, qkvT, 1536, 1024, 512, 0L, 524288L);
  attn_mfma<<<dim3(16, 128), 256, 0, stream>>>(qkvT, aT);
  gemm_tn<float, false><<<dim3(4, 8, 16), 256, 0, stream>>>(
      aT, wp, b_proj, out, 1024, 512, 512, 524288L, 0L);
}

// Round 8
// 242.312 us; speedup vs baseline: 4.2910x; 1.0091x over previous
//
#include <hip/hip_runtime.h>
#include <math.h>

// ---------------------------------------------------------------------------
// AttentionBlock: GroupNorm(32) -> QKV proj -> MHA(8 heads) -> out proj
// B=16, C=512, L=1024, group=16ch, head ch=64.
// Round 8: (a) GEMM epilogue via LDS transpose -> coalesced row stores
//          (b) attn t-tile 128 (2 col-groups/wave) -> staging+barriers /2
// ---------------------------------------------------------------------------

typedef _Float16 f16x8 __attribute__((ext_vector_type(8)));
typedef _Float16 f16x4 __attribute__((ext_vector_type(4)));
typedef float f32x4 __attribute__((ext_vector_type(4)));

// NOTE: legacy K=16 fp16 MFMA builtin has NO underscore before f16.
#define MFMA_K16(A, B, C) __builtin_amdgcn_mfma_f32_16x16x16f16(A, B, C, 0, 0, 0)

// async 16B/lane global->LDS copy. LDS dest is WAVE-UNIFORM base; HW places
// lane i at base + i*16. Global src is per-lane.
__device__ __forceinline__ void async_cp16(const void* g, void* l) {
  __builtin_amdgcn_global_load_lds(
      (const __attribute__((address_space(1))) void*)g,
      (__attribute__((address_space(3))) void*)l, 16, 0, 0);
}

// ------------------------- weight fp32 -> fp16 ------------------------------
__global__ __launch_bounds__(256) void f32_to_f16(
    const float* __restrict__ src, _Float16* __restrict__ dst, int n4) {
  int i = blockIdx.x * 256 + threadIdx.x;
  if (i < n4) {
    float4 v = ((const float4*)src)[i];
    f16x4 o = {(_Float16)v.x, (_Float16)v.y, (_Float16)v.z, (_Float16)v.w};
    *(f16x4*)&dst[(size_t)i * 4] = o;
  }
}

// ------------------------- GroupNorm (writes hT [b][l][c] fp16) -------------
__global__ __launch_bounds__(256) void gn_kernel(
    const float* __restrict__ x, const float* __restrict__ gw,
    const float* __restrict__ gb, _Float16* __restrict__ hT) {
  const int b = blockIdx.x >> 5;
  const int g = blockIdx.x & 31;
  const size_t base = ((size_t)(b * 512 + g * 16)) * 1024;
  const float4* xp = (const float4*)(x + base);
  const int tid = threadIdx.x;

  float4 vals[16];
  float s = 0.f, sq = 0.f;
#pragma unroll
  for (int r = 0; r < 16; ++r) {
    float4 v = xp[tid + 256 * r];
    vals[r] = v;
    s += v.x + v.y + v.z + v.w;
    sq += v.x * v.x + v.y * v.y + v.z * v.z + v.w * v.w;
  }
  __shared__ float rs[256];
  __shared__ float rq[256];
  rs[tid] = s;
  rq[tid] = sq;
  __syncthreads();
  for (int off = 128; off > 0; off >>= 1) {
    if (tid < off) {
      rs[tid] += rs[tid + off];
      rq[tid] += rq[tid + off];
    }
    __syncthreads();
  }
  const float mean = rs[0] * (1.f / 16384.f);
  const float var = rq[0] * (1.f / 16384.f) - mean * mean;
  const float rinv = rsqrtf(var + 1e-5f);
#pragma unroll
  for (int r = 0; r < 16; ++r) {
    const int c = g * 16 + r;
    const float wc = gw[c] * rinv;
    const float bc = gb[c] - mean * wc;
    vals[r].x = vals[r].x * wc + bc;
    vals[r].y = vals[r].y * wc + bc;
    vals[r].z = vals[r].z * wc + bc;
    vals[r].w = vals[r].w * wc + bc;
  }
  _Float16* hb = hT + ((size_t)b * 1024 + tid * 4) * 512 + g * 16;
#pragma unroll
  for (int li = 0; li < 4; ++li) {
    f16x8 o0, o1;
#pragma unroll
    for (int r = 0; r < 8; ++r) {
      float v0 = li == 0 ? vals[r].x : li == 1 ? vals[r].y
                 : li == 2 ? vals[r].z : vals[r].w;
      float v1 = li == 0 ? vals[8 + r].x : li == 1 ? vals[8 + r].y
                 : li == 2 ? vals[8 + r].z : vals[8 + r].w;
      o0[r] = (_Float16)v0;
      o1[r] = (_Float16)v1;
    }
    *(f16x8*)(hb + (size_t)li * 512) = o0;
    *(f16x8*)(hb + (size_t)li * 512 + 8) = o1;
  }
}

// ------------------------- fp16 MFMA GEMM, async staging --------------------
// C[m][n] = sum_k A[m][k]*B[n][k] (+bias), stored TRANSPOSED: Out[n][m].
// 128x128 tile, BK=32, async global->LDS staging.
// Epilogue: C-frags (+bias) -> LDS [n][m] tile -> coalesced row stores.
template <typename OutT, bool BIAS_ON_M>
__global__ __launch_bounds__(256) void gemm_tn(
    const _Float16* __restrict__ A, const _Float16* __restrict__ B,
    const float* __restrict__ bias, OutT* __restrict__ Out,
    int M, int N, int K, long sA, long sB) {
  __shared__ __align__(16) char smem[34816];  // As(8K)+Bs(8K) | T(34.8K)
  _Float16* As = (_Float16*)smem;
  _Float16* Bs = As + 128 * 32;
  const int tid = threadIdx.x;
  const int w = tid >> 6, lane = tid & 63;
  const int lx = lane & 15, quad = lane >> 4;
  const int wm = w >> 1, wn = w & 1;
  const int bn = blockIdx.x * 128, bm = blockIdx.y * 128;
  const int z = blockIdx.z;

  // staging: chunk0 rows [w*16, w*16+16), chunk1 rows +64; 16B/lane
  const int cr = w * 16;
  const int lrow = lane >> 2;
  const int lk = (lane & 3) * 8;
  const _Float16* Ag = A + (size_t)z * sA + (size_t)(bm + cr + lrow) * K + lk;
  const _Float16* Bg = B + (size_t)z * sB + (size_t)(bn + cr + lrow) * K + lk;
  _Float16* As0 = &As[cr * 32];
  _Float16* As1 = &As[(cr + 64) * 32];
  _Float16* Bs0 = &Bs[cr * 32];
  _Float16* Bs1 = &Bs[(cr + 64) * 32];

  f32x4 acc[4][4];
#pragma unroll
  for (int i = 0; i < 4; ++i)
#pragma unroll
    for (int j = 0; j < 4; ++j) acc[i][j] = (f32x4){0.f, 0.f, 0.f, 0.f};

  for (int k0 = 0; k0 < K; k0 += 32) {
    __syncthreads();
    async_cp16(Ag + k0, As0);
    async_cp16(Ag + (size_t)64 * K + k0, As1);
    async_cp16(Bg + k0, Bs0);
    async_cp16(Bg + (size_t)64 * K + k0, Bs1);
    __syncthreads();
    f16x8 af[4], bf[4];
#pragma unroll
    for (int mt = 0; mt < 4; ++mt)
      af[mt] = *(const f16x8*)&As[(wm * 64 + mt * 16 + lx) * 32 + quad * 8];
#pragma unroll
    for (int nt = 0; nt < 4; ++nt)
      bf[nt] = *(const f16x8*)&Bs[(wn * 64 + nt * 16 + lx) * 32 + quad * 8];
#pragma unroll
    for (int mt = 0; mt < 4; ++mt)
#pragma unroll
      for (int nt = 0; nt < 4; ++nt)
        acc[mt][nt] = __builtin_amdgcn_mfma_f32_16x16x32_f16(
            af[mt], bf[nt], acc[mt][nt], 0, 0, 0);
  }

  OutT* Ob = Out + (size_t)z * M * N;
  if constexpr (sizeof(OutT) == 2) {
    // ---- f16 out: single-pass 128x128 transpose tile, stride 136 ----
    _Float16* T = (_Float16*)smem;
    __syncthreads();  // K-loop LDS reads done
#pragma unroll
    for (int mt = 0; mt < 4; ++mt) {
      const int m0 = bm + wm * 64 + mt * 16 + quad * 4;
      float bm4[4];
#pragma unroll
      for (int i = 0; i < 4; ++i) bm4[i] = BIAS_ON_M ? bias[m0 + i] : 0.f;
#pragma unroll
      for (int nt = 0; nt < 4; ++nt) {
        const int nl = wn * 64 + nt * 16 + lx;
        const float bn1 = BIAS_ON_M ? 0.f : bias[bn + nl];
        f16x4 o = {(_Float16)(acc[mt][nt][0] + (BIAS_ON_M ? bm4[0] : bn1)),
                   (_Float16)(acc[mt][nt][1] + (BIAS_ON_M ? bm4[1] : bn1)),
                   (_Float16)(acc[mt][nt][2] + (BIAS_ON_M ? bm4[2] : bn1)),
                   (_Float16)(acc[mt][nt][3] + (BIAS_ON_M ? bm4[3] : bn1))};
        *(f16x4*)&T[nl * 136 + wm * 64 + mt * 16 + quad * 4] = o;
      }
    }
    __syncthreads();
#pragma unroll
    for (int j = 0; j < 8; ++j) {
      const int r = j * 16 + (tid >> 4), slot = tid & 15;
      f16x8 vv = *(const f16x8*)&T[r * 136 + slot * 8];
      *(f16x8*)((_Float16*)Ob + (size_t)(bn + r) * M + bm + slot * 8) = vv;
    }
  } else {
    // ---- f32 out: two half-passes (64 n-rows each), stride 136 ----
    float* T32 = (float*)smem;
#pragma unroll
    for (int p = 0; p < 2; ++p) {
      __syncthreads();
      if (wn == p) {
#pragma unroll
        for (int mt = 0; mt < 4; ++mt) {
          const int m0 = bm + wm * 64 + mt * 16 + quad * 4;
          float bm4[4];
#pragma unroll
          for (int i = 0; i < 4; ++i) bm4[i] = BIAS_ON_M ? bias[m0 + i] : 0.f;
#pragma unroll
          for (int nt = 0; nt < 4; ++nt) {
            const int nl = nt * 16 + lx;
            const float bn1 = BIAS_ON_M ? 0.f : bias[bn + p * 64 + nl];
            float4 o = {acc[mt][nt][0] + (BIAS_ON_M ? bm4[0] : bn1),
                        acc[mt][nt][1] + (BIAS_ON_M ? bm4[1] : bn1),
                        acc[mt][nt][2] + (BIAS_ON_M ? bm4[2] : bn1),
                        acc[mt][nt][3] + (BIAS_ON_M ? bm4[3] : bn1)};
            *(float4*)&T32[nl * 136 + wm * 64 + mt * 16 + quad * 4] = o;
          }
        }
      }
      __syncthreads();
#pragma unroll
      for (int j = 0; j < 8; ++j) {
        const int r = j * 8 + (tid >> 5), slot = tid & 31;
        float4 vv = *(const float4*)&T32[r * 136 + slot * 4];
        *(float4*)((float*)Ob + (size_t)(bn + p * 64 + r) * M + bm + slot * 4) =
            vv;
      }
    }
  }
}

// ------------------------- fp16 MFMA flash attention ------------------------
// qkvT layout: [b][l][o], o = h*192 + {0..63 q, 64..127 k, 128..191 v}.
// Block = (b,h) x 128 t-tile, 4 waves; wave w owns t-cols w*32+{0..15,16..31}
// (2 groups), full s. Per staged 64-s tile: S^T = mfma32(A=K, B=Q_g) — K-frag
// read once serves both groups; C-frag feeds PV directly (K=16 B-operand);
// V-frag read once serves both groups. Staging/barriers per output halved.
#define LQ 72
#define LV 68

__global__ __launch_bounds__(256) void attn_mfma(
    const _Float16* __restrict__ qkvT, _Float16* __restrict__ aT) {
  __shared__ __align__(16) _Float16 ks[64 * LQ];  // [s][ch]  9216 B
  __shared__ __align__(16) _Float16 vs[64 * LV];  // [ch][s]  8704 B

  const int tid = threadIdx.x;
  const int w = tid >> 6, lane = tid & 63;
  const int lx = lane & 15, quad = lane >> 4;
  const int bh = blockIdx.y, b = bh >> 3, h = bh & 7;
  const int t0 = blockIdx.x * 128;
  const _Float16* qb = qkvT + (size_t)b * 1024 * 1536 + h * 192;

  // ---- Q B-frags from global (once), scale 1/8 folded in ----
  f16x8 qf[2][2];
#pragma unroll
  for (int g = 0; g < 2; ++g) {
    const _Float16* qrow = qb + (size_t)(t0 + w * 32 + g * 16 + lx) * 1536;
    qf[g][0] = *(const f16x8*)(qrow + quad * 8);
    qf[g][1] = *(const f16x8*)(qrow + 32 + quad * 8);
#pragma unroll
    for (int j = 0; j < 8; ++j) {
      qf[g][0][j] = qf[g][0][j] * (_Float16)0.125f;
      qf[g][1][j] = qf[g][1][j] * (_Float16)0.125f;
    }
  }

  float m_r[2] = {-1e30f, -1e30f}, l_r[2] = {0.f, 0.f};
  f32x4 oacc[2][4];  // [g][mt]: D[m=ch: mt*16+quad*4+i][n=t: w*32+g*16+lx]
#pragma unroll
  for (int g = 0; g < 2; ++g)
#pragma unroll
    for (int mt = 0; mt < 4; ++mt) oacc[g][mt] = (f32x4){0.f, 0.f, 0.f, 0.f};

  for (int s0 = 0; s0 < 1024; s0 += 64) {
    __syncthreads();  // prior tile's fragment reads complete
    // ---- stage K [s][ch]: direct row copy ----
    {
      const int r = tid >> 2, c = (tid & 3) * 16;
      const _Float16* g = qb + (size_t)(s0 + r) * 1536 + 64 + c;
      *(f16x8*)&ks[r * LQ + c] = *(const f16x8*)g;
      *(f16x8*)&ks[r * LQ + c + 8] = *(const f16x8*)(g + 8);
    }
    // ---- stage V transposed [ch][s], s-pairs packed b32 ----
    {
      const int s2 = (tid >> 3) * 2, c8 = (tid & 7) * 8;
      const _Float16* g = qb + (size_t)(s0 + s2) * 1536 + 128 + c8;
      f16x8 v0 = *(const f16x8*)g;
      f16x8 v1 = *(const f16x8*)(g + 1536);
#pragma unroll
      for (int i = 0; i < 8; ++i) {
        union { _Float16 hh[2]; unsigned u; } p;
        p.hh[0] = v0[i];
        p.hh[1] = v1[i];
        *(unsigned*)&vs[(c8 + i) * LV + s2] = p.u;
      }
    }
    __syncthreads();

    // ---- S^T[s][t] both groups; K-frags read once per sb ----
    f32x4 sf[2][4];
#pragma unroll
    for (int sb = 0; sb < 4; ++sb) {
      f16x8 k0 = *(const f16x8*)&ks[(sb * 16 + lx) * LQ + quad * 8];
      f16x8 k1 = *(const f16x8*)&ks[(sb * 16 + lx) * LQ + 32 + quad * 8];
#pragma unroll
      for (int g = 0; g < 2; ++g) {
        f32x4 z = {0.f, 0.f, 0.f, 0.f};
        z = __builtin_amdgcn_mfma_f32_16x16x32_f16(k0, qf[g][0], z, 0, 0, 0);
        sf[g][sb] =
            __builtin_amdgcn_mfma_f32_16x16x32_f16(k1, qf[g][1], z, 0, 0, 0);
      }
    }

    // ---- online softmax per group (lane-scalar m/l) ----
    f16x4 pf[2][4];
#pragma unroll
    for (int g = 0; g < 2; ++g) {
      float mx = sf[g][0][0];
#pragma unroll
      for (int sb = 0; sb < 4; ++sb)
#pragma unroll
        for (int i = 0; i < 4; ++i) mx = fmaxf(mx, sf[g][sb][i]);
      mx = fmaxf(mx, __shfl_xor(mx, 16));
      mx = fmaxf(mx, __shfl_xor(mx, 32));
      const float mn = fmaxf(m_r[g], mx);
      const float alpha = __expf(m_r[g] - mn);
      m_r[g] = mn;
      float sum = 0.f;
#pragma unroll
      for (int sb = 0; sb < 4; ++sb) {
        float p0 = __expf(sf[g][sb][0] - mn);
        float p1 = __expf(sf[g][sb][1] - mn);
        float p2 = __expf(sf[g][sb][2] - mn);
        float p3 = __expf(sf[g][sb][3] - mn);
        sum += (p0 + p1) + (p2 + p3);
        pf[g][sb] =
            (f16x4){(_Float16)p0, (_Float16)p1, (_Float16)p2, (_Float16)p3};
      }
      sum += __shfl_xor(sum, 16);
      sum += __shfl_xor(sum, 32);
      l_r[g] = l_r[g] * alpha + sum;
      if (!__all(alpha == 1.f)) {
#pragma unroll
        for (int mt = 0; mt < 4; ++mt)
#pragma unroll
          for (int i = 0; i < 4; ++i) oacc[g][mt][i] *= alpha;
      }
    }

    // ---- PV: V-frag read once serves both groups ----
#pragma unroll
    for (int kb = 0; kb < 4; ++kb)
#pragma unroll
      for (int mt = 0; mt < 4; ++mt) {
        f16x4 vf = *(const f16x4*)&vs[(mt * 16 + lx) * LV + kb * 16 + quad * 4];
        oacc[0][mt] = MFMA_K16(vf, pf[0][kb], oacc[0][mt]);
        oacc[1][mt] = MFMA_K16(vf, pf[1][kb], oacc[1][mt]);
      }
  }

  // ---- epilogue: aT[b][t][h*64+ch] = O/l (all lane-local) ----
#pragma unroll
  for (int g = 0; g < 2; ++g) {
    const float linv = 1.f / l_r[g];
    _Float16* ob =
        aT + ((size_t)b * 1024 + t0 + w * 32 + g * 16 + lx) * 512 + h * 64;
#pragma unroll
    for (int mt = 0; mt < 4; ++mt) {
      f16x4 o = {(_Float16)(oacc[g][mt][0] * linv),
                 (_Float16)(oacc[g][mt][1] * linv),
                 (_Float16)(oacc[g][mt][2] * linv),
                 (_Float16)(oacc[g][mt][3] * linv)};
      *(f16x4*)&ob[mt * 16 + quad * 4] = o;
    }
  }
}

// ---------------------------------------------------------------------------
extern "C" void kernel_launch(void* const* d_in, const int* in_sizes, int n_in,
                              void* d_out, int out_size, void* d_ws,
                              size_t ws_size, hipStream_t stream) {
  const float* x = (const float*)d_in[0];
  const float* norm_w = (const float*)d_in[1];
  const float* norm_b = (const float*)d_in[2];
  const float* w_qkv = (const float*)d_in[3];
  const float* b_qkv = (const float*)d_in[4];
  const float* w_proj = (const float*)d_in[5];
  const float* b_proj = (const float*)d_in[6];
  float* out = (float*)d_out;

  _Float16* hT = (_Float16*)d_ws;
  _Float16* qkvT = hT + (size_t)16 * 1024 * 512;
  _Float16* wq = qkvT + (size_t)16 * 1024 * 1536;
  _Float16* wp = wq + (size_t)1536 * 512;
  _Float16* aT = hT;

  f32_to_f16<<<768, 256, 0, stream>>>(w_qkv, wq, 196608);
  f32_to_f16<<<256, 256, 0, stream>>>(w_proj, wp, 65536);
  gn_kernel<<<512, 256, 0, stream>>>(x, norm_w, norm_b, hT);
  gemm_tn<_Float16, true><<<dim3(8, 12, 16), 256, 0, stream>>>(
      wq, hT, b_qkv, qkvT, 1536, 1024, 512, 0L, 524288L);
  attn_mfma<<<dim3(8, 128), 256, 0, stream>>>(qkvT, aT);
  gemm_tn<float, false><<<dim3(4, 8, 16), 256, 0, stream>>>(
      aT, wp, b_proj, out, 1024, 512, 512, 524288L, 0L);
}